// Round 8
// baseline (281.159 us; speedup 1.0000x reference)
//
#include <hip/hip_runtime.h>

// B=4, L=2048, D=1024, H=16, HD=64.
// d_in fp32: x, Wqkv, bqkv, Wproj, bproj. d_out fp32.
// Pipeline: one-time fp32->bf16 conversion, m97-style bf16 MFMA GEMMs with
// global_load_lds, and swapped-operand LDS-free causal flash attention:
// anti-diagonal pair-balanced + split-K across the block's 2 waves with an
// LDS flash-decoding merge. Zero-shuffle P pack via bit2<->3-permuted V^T.

typedef __bf16 bf16x2 __attribute__((ext_vector_type(2)));
typedef __bf16 bf16x8 __attribute__((ext_vector_type(8)));
typedef float f32x4 __attribute__((ext_vector_type(4)));
typedef float f32x16 __attribute__((ext_vector_type(16)));
typedef unsigned u32x4 __attribute__((ext_vector_type(4)));

#define MFMA16(a, b, c) __builtin_amdgcn_mfma_f32_16x16x32_bf16(a, b, c, 0, 0, 0)
#define MFMA32(a, b, c) __builtin_amdgcn_mfma_f32_32x32x16_bf16(a, b, c, 0, 0, 0)

__device__ __forceinline__ void gload_lds16(const __bf16* g, __bf16* l) {
    __builtin_amdgcn_global_load_lds(
        (const __attribute__((address_space(1))) void*)g,
        (__attribute__((address_space(3))) void*)l, 16, 0, 0);
}

__device__ __forceinline__ unsigned pkbf(float a, float b) {
    bf16x2 t = {(__bf16)a, (__bf16)b};
    return __builtin_bit_cast(unsigned, t);
}

// ---------------------------------------------------------------------------
__global__ void convert_kernel(const float* __restrict__ in, __bf16* __restrict__ out)
{
    int i = (blockIdx.x * 256 + threadIdx.x) * 8;
    f32x4 lo = *(const f32x4*)&in[i];
    f32x4 hi = *(const f32x4*)&in[i + 4];
    bf16x8 o;
#pragma unroll
    for (int j = 0; j < 4; ++j) { o[j] = (__bf16)lo[j]; o[j + 4] = (__bf16)hi[j]; }
    *(bf16x8*)&out[i] = o;
}

// ---------------------------------------------------------------------------
__global__ void transpose_convert_kernel(const float* __restrict__ in,
                                         __bf16* __restrict__ out, int R, int C)
{
    __shared__ __bf16 t[32][33];
    const int c0 = blockIdx.x * 32, r0 = blockIdx.y * 32;
    const int tx = threadIdx.x & 31, ty = threadIdx.x >> 5;
#pragma unroll
    for (int j = 0; j < 4; ++j) {
        int r = ty + j * 8;
        t[tx][r] = (__bf16)in[(size_t)(r0 + r) * C + c0 + tx];
    }
    __syncthreads();
#pragma unroll
    for (int j = 0; j < 4; ++j) {
        int r = ty + j * 8;
        out[(size_t)(c0 + r) * R + r0 + tx] = t[r][tx];
    }
}

// ---------------------------------------------------------------------------
// m97-style GEMM core (unchanged).
// ---------------------------------------------------------------------------
#define GEMM_TILE_LOOP(Abase, Bbase)                                               \
    for (int k0 = 0; k0 < 1024; k0 += 32) {                                        \
        __syncthreads();                                                           \
        _Pragma("unroll")                                                          \
        for (int i = 0; i < 2; ++i) {                                              \
            int wl = w * 2 + i;                                                    \
            int r = wl * 16 + (lane >> 2);                                         \
            int c = ((lane & 3) ^ ((r >> 1) & 3)) * 8;                             \
            gload_lds16(&Abase[(size_t)(m0 + r) * 1024 + k0 + c], &As[wl * 512]);  \
            gload_lds16(&Bbase[(size_t)(n0 + r) * 1024 + k0 + c], &Bs[wl * 512]);  \
        }                                                                          \
        __syncthreads();                                                           \
        bf16x8 af[4], bfr[4];                                                      \
        _Pragma("unroll")                                                          \
        for (int mf = 0; mf < 4; ++mf) {                                           \
            int rr = wr * 64 + mf * 16 + row;                                      \
            af[mf] = *(const bf16x8*)&As[rr * 32 + ((g ^ ((rr >> 1) & 3)) * 8)];   \
        }                                                                          \
        _Pragma("unroll")                                                          \
        for (int nf = 0; nf < 4; ++nf) {                                           \
            int rr = wc * 64 + nf * 16 + row;                                      \
            bfr[nf] = *(const bf16x8*)&Bs[rr * 32 + ((g ^ ((rr >> 1) & 3)) * 8)];  \
        }                                                                          \
        _Pragma("unroll")                                                          \
        for (int mf = 0; mf < 4; ++mf)                                             \
            _Pragma("unroll")                                                      \
            for (int nf = 0; nf < 4; ++nf)                                         \
                acc[mf][nf] = MFMA16(af[mf], bfr[nf], acc[mf][nf]);                \
    }

// QKV: q(SCALED),k -> [B,H,L,64]; v -> [B,H,64,L] with k bits 2<->3 swapped.
__global__ __launch_bounds__(256, 2)
void qkv_gemm_kernel(const __bf16* __restrict__ A, const __bf16* __restrict__ Bt,
                     const float* __restrict__ bias,
                     __bf16* __restrict__ qo, __bf16* __restrict__ ko,
                     __bf16* __restrict__ vt)
{
    __shared__ __bf16 As[128 * 32];
    __shared__ __bf16 Bs[128 * 32];
    const int tid = threadIdx.x;
    const int lane = tid & 63;
    const int w = tid >> 6;
    const int wr = w >> 1, wc = w & 1;
    const int row = lane & 15, g = lane >> 4;
    const int m0 = blockIdx.x * 128;
    const int n0 = blockIdx.y * 128;

    const f32x4 fzero = {0.f, 0.f, 0.f, 0.f};
    f32x4 acc[4][4];
#pragma unroll
    for (int a = 0; a < 4; ++a)
#pragma unroll
        for (int b = 0; b < 4; ++b) acc[a][b] = fzero;

    GEMM_TILE_LOOP(A, Bt)

    const float QSCL = 0.18033688f;   // 0.125 * log2(e)
#pragma unroll
    for (int mf = 0; mf < 4; ++mf)
#pragma unroll
        for (int nf = 0; nf < 4; ++nf) {
            int n = n0 + wc * 64 + nf * 16 + row;
            int part = n >> 10;
            int d = n & 1023;
            int h = d >> 6, hd = d & 63;
            float bv = bias[n];
#pragma unroll
            for (int i = 0; i < 4; ++i) {
                int mm = m0 + wr * 64 + mf * 16 + g * 4 + i;
                int b = mm >> 11, l = mm & 2047;
                float fv = acc[mf][nf][i] + bv;
                if (part == 0)
                    qo[(((size_t)(b * 16 + h) * 2048) + l) * 64 + hd] =
                        (__bf16)(fv * QSCL);
                else if (part == 1)
                    ko[(((size_t)(b * 16 + h) * 2048) + l) * 64 + hd] = (__bf16)fv;
                else {
                    int lp = (l & ~12) | ((l & 4) << 1) | ((l & 8) >> 1);
                    vt[(((size_t)(b * 16 + h) * 64) + hd) * 2048 + lp] = (__bf16)fv;
                }
            }
        }
}

__global__ __launch_bounds__(256, 2)
void proj_gemm_kernel(const __bf16* __restrict__ A, const __bf16* __restrict__ Bt,
                      const float* __restrict__ bias, float* __restrict__ out)
{
    __shared__ __bf16 As[128 * 32];
    __shared__ __bf16 Bs[128 * 32];
    const int tid = threadIdx.x;
    const int lane = tid & 63;
    const int w = tid >> 6;
    const int wr = w >> 1, wc = w & 1;
    const int row = lane & 15, g = lane >> 4;
    const int m0 = blockIdx.x * 128;
    const int n0 = blockIdx.y * 128;

    const f32x4 fzero = {0.f, 0.f, 0.f, 0.f};
    f32x4 acc[4][4];
#pragma unroll
    for (int a = 0; a < 4; ++a)
#pragma unroll
        for (int b = 0; b < 4; ++b) acc[a][b] = fzero;

    GEMM_TILE_LOOP(A, Bt)

#pragma unroll
    for (int mf = 0; mf < 4; ++mf)
#pragma unroll
        for (int nf = 0; nf < 4; ++nf) {
            int n = n0 + wc * 64 + nf * 16 + row;
            float bv = bias[n];
#pragma unroll
            for (int i = 0; i < 4; ++i) {
                int mm = m0 + wr * 64 + mf * 16 + g * 4 + i;
                out[(size_t)mm * 1024 + n] = acc[mf][nf][i] + bv;
            }
        }
}

// ---------------------------------------------------------------------------
// Split-K pair-balanced swapped-operand causal flash attention.
// Grid (32, B*H=64), 128 thr = 2 waves. Block owns q-tiles t=blockIdx.x and
// 63-t; wave 0 does the first half of each tile's k-range, wave 1 the second
// (~32.5 units each). Per-wave loop identical to round-7 dual-chain zip with
// per-chain kb. LDS flash-decoding merge: wave1 posts chain-A partials,
// wave0 posts chain-B; one barrier; wave0 merges+writes A, wave1 writes B.
// ---------------------------------------------------------------------------
__global__ __launch_bounds__(128, 2)
void attn_kernel(const __bf16* __restrict__ Qw, const __bf16* __restrict__ Kw,
                 const __bf16* __restrict__ Vt, __bf16* __restrict__ Yw)
{
    __shared__ float LmA[64], LlA[64], LOA[64][33];
    __shared__ float LmB[64], LlB[64], LOB[64][33];

    const int tid = threadIdx.x;
    const int lane = tid & 63;
    const int wv = tid >> 6;
    const int col = lane & 31;
    const int hi = lane >> 5;
    const int bh = blockIdx.y;
    const int t = blockIdx.x;                 // 0..31
    const int qA = t * 32;
    const int qB = (63 - t) * 32;
    const __bf16* Q = Qw + (size_t)bh * 2048 * 64;
    const __bf16* K = Kw + (size_t)bh * 2048 * 64;
    const __bf16* V = Vt + (size_t)bh * 64 * 2048;   // [64 d][2048 k] (k-perm)

    // k-range halves
    const int nA = t + 1, nB = 64 - t;
    const int hA = (nA + 1) >> 1, hB = (nB + 1) >> 1;
    const int sA = wv ? hA : 0, eA = wv ? nA : hA;
    const int sB = wv ? hB : 0, eB = wv ? nB : hB;
    const int lenA = eA - sA, lenB = eB - sB;
    const int steps = lenA > lenB ? lenA : lenB;

    bf16x8 qfA[4], qfB[4];
#pragma unroll
    for (int dc = 0; dc < 4; ++dc) {
        qfA[dc] = *(const bf16x8*)&Q[(size_t)(qA + col) * 64 + dc * 16 + hi * 8];
        qfB[dc] = *(const bf16x8*)&Q[(size_t)(qB + col) * 64 + dc * 16 + hi * 8];
    }

    f32x16 OtA[2], OtB[2];
#pragma unroll
    for (int dt = 0; dt < 2; ++dt)
#pragma unroll
        for (int i = 0; i < 16; ++i) { OtA[dt][i] = 0.f; OtB[dt][i] = 0.f; }
    float mA = -__builtin_inff(), lA = 0.f;
    float mB = -__builtin_inff(), lB = 0.f;

    auto smxpack = [&](f32x16& st, float& m, float& lsum, f32x16* Ot,
                       bool diag, bf16x8& pa0, bf16x8& pa1) {
        if (diag) {
#pragma unroll
            for (int r = 0; r < 16; ++r) {
                int crow = (r & 3) + 8 * (r >> 2) + 4 * hi;
                if (crow > col) st[r] = -1e30f;
            }
        }
        float a0 = fmaxf(fmaxf(st[0], st[1]), st[2]);
        float a1 = fmaxf(fmaxf(st[3], st[4]), st[5]);
        float a2 = fmaxf(fmaxf(st[6], st[7]), st[8]);
        float a3 = fmaxf(fmaxf(st[9], st[10]), st[11]);
        float a4 = fmaxf(st[12], st[13]);
        float a5 = fmaxf(st[14], st[15]);
        float pmax = fmaxf(fmaxf(fmaxf(a0, a1), fmaxf(a2, a3)), fmaxf(a4, a5));
        pmax = fmaxf(pmax, __shfl_xor(pmax, 32, 64));
        if (!__all(pmax - m <= 8.0f)) {
            float mnew = fmaxf(m, pmax);
            float alpha = exp2f(m - mnew);
#pragma unroll
            for (int dt = 0; dt < 2; ++dt)
#pragma unroll
                for (int i = 0; i < 16; ++i) Ot[dt][i] *= alpha;
            lsum *= alpha;
            m = mnew;
        }
#pragma unroll
        for (int r = 0; r < 16; ++r) st[r] = exp2f(st[r] - m);
        float s0 = (st[0] + st[1]) + (st[2] + st[3]);
        float s1 = (st[4] + st[5]) + (st[6] + st[7]);
        float s2 = (st[8] + st[9]) + (st[10] + st[11]);
        float s3 = (st[12] + st[13]) + (st[14] + st[15]);
        float rs = (s0 + s1) + (s2 + s3);
        rs += __shfl_xor(rs, 32, 64);
        lsum += rs;
        u32x4 w0 = {pkbf(st[0], st[1]), pkbf(st[2], st[3]),
                    pkbf(st[4], st[5]), pkbf(st[6], st[7])};
        u32x4 w1 = {pkbf(st[8], st[9]), pkbf(st[10], st[11]),
                    pkbf(st[12], st[13]), pkbf(st[14], st[15])};
        pa0 = __builtin_bit_cast(bf16x8, w0);
        pa1 = __builtin_bit_cast(bf16x8, w1);
    };

    for (int i = 0; i < steps; ++i) {
        const bool aA = i < lenA, aB = i < lenB;
        const int kbA = (sA + i) << 5, kbB = (sB + i) << 5;

        bf16x8 kfA[4], kfB[4], vfA[4], vfB[4];
        if (aA) {
#pragma unroll
            for (int dc = 0; dc < 4; ++dc)
                kfA[dc] = *(const bf16x8*)&K[(size_t)(kbA + col) * 64 + dc * 16 + hi * 8];
#pragma unroll
            for (int dt = 0; dt < 2; ++dt) {
                vfA[dt * 2 + 0] = *(const bf16x8*)&V[(size_t)(dt * 32 + col) * 2048 + kbA + hi * 8];
                vfA[dt * 2 + 1] = *(const bf16x8*)&V[(size_t)(dt * 32 + col) * 2048 + kbA + 16 + hi * 8];
            }
        }
        if (aB) {
#pragma unroll
            for (int dc = 0; dc < 4; ++dc)
                kfB[dc] = *(const bf16x8*)&K[(size_t)(kbB + col) * 64 + dc * 16 + hi * 8];
#pragma unroll
            for (int dt = 0; dt < 2; ++dt) {
                vfB[dt * 2 + 0] = *(const bf16x8*)&V[(size_t)(dt * 32 + col) * 2048 + kbB + hi * 8];
                vfB[dt * 2 + 1] = *(const bf16x8*)&V[(size_t)(dt * 32 + col) * 2048 + kbB + 16 + hi * 8];
            }
        }

        f32x16 stA, stB;
#pragma unroll
        for (int i2 = 0; i2 < 16; ++i2) { stA[i2] = 0.f; stB[i2] = 0.f; }
        __builtin_amdgcn_s_setprio(1);
#pragma unroll
        for (int dc = 0; dc < 4; ++dc) {
            if (aB) stB = MFMA32(kfB[dc], qfB[dc], stB);
            if (aA) stA = MFMA32(kfA[dc], qfA[dc], stA);
        }
        __builtin_amdgcn_s_setprio(0);

        bf16x8 paA0, paA1, paB0, paB1;
        if (aB) smxpack(stB, mB, lB, OtB, kbB == qB, paB0, paB1);
        if (aA) smxpack(stA, mA, lA, OtA, kbA == qA, paA0, paA1);

        __builtin_amdgcn_s_setprio(1);
#pragma unroll
        for (int dt = 0; dt < 2; ++dt) {
            if (aB) {
                OtB[dt] = MFMA32(vfB[dt * 2 + 0], paB0, OtB[dt]);
                OtB[dt] = MFMA32(vfB[dt * 2 + 1], paB1, OtB[dt]);
            }
            if (aA) {
                OtA[dt] = MFMA32(vfA[dt * 2 + 0], paA0, OtA[dt]);
                OtA[dt] = MFMA32(vfA[dt * 2 + 1], paA1, OtA[dt]);
            }
        }
        __builtin_amdgcn_s_setprio(0);
    }

    // ---- post partials: wave1 posts chain A, wave0 posts chain B
    if (wv == 1) {
        LmA[lane] = mA; LlA[lane] = lA;
#pragma unroll
        for (int dt = 0; dt < 2; ++dt)
#pragma unroll
            for (int r = 0; r < 16; ++r) LOA[lane][dt * 16 + r] = OtA[dt][r];
    } else {
        LmB[lane] = mB; LlB[lane] = lB;
#pragma unroll
        for (int dt = 0; dt < 2; ++dt)
#pragma unroll
            for (int r = 0; r < 16; ++r) LOB[lane][dt * 16 + r] = OtB[dt][r];
    }
    __syncthreads();

    // ---- merge + write (wave0: chain A rows; wave1: chain B rows)
    const int b = bh >> 4, h = bh & 15;
    float mo, lo_, m1, l1;
    f32x16* Oo;
    float* LOrow;
    int qrow;
    if (wv == 0) {
        mo = mA; lo_ = lA; Oo = OtA;
        m1 = LmA[lane]; l1 = LlA[lane]; LOrow = LOA[lane]; qrow = qA;
    } else {
        mo = mB; lo_ = lB; Oo = OtB;
        m1 = LmB[lane]; l1 = LlB[lane]; LOrow = LOB[lane]; qrow = qB;
    }
    float ms = fmaxf(mo, m1);
    float c0 = exp2f(mo - ms), c1 = exp2f(m1 - ms);
    float inv = 1.f / (lo_ * c0 + l1 * c1);
    __bf16* yrow = Yw + ((size_t)(b * 2048 + qrow + col)) * 1024 + h * 64;
#pragma unroll
    for (int dt = 0; dt < 2; ++dt)
#pragma unroll
        for (int rg = 0; rg < 4; ++rg) {
            int d0 = dt * 32 + rg * 8 + hi * 4;
            float v0 = (Oo[dt][rg * 4 + 0] * c0 + LOrow[dt * 16 + rg * 4 + 0] * c1) * inv;
            float v1 = (Oo[dt][rg * 4 + 1] * c0 + LOrow[dt * 16 + rg * 4 + 1] * c1) * inv;
            float v2 = (Oo[dt][rg * 4 + 2] * c0 + LOrow[dt * 16 + rg * 4 + 2] * c1) * inv;
            float v3 = (Oo[dt][rg * 4 + 3] * c0 + LOrow[dt * 16 + rg * 4 + 3] * c1) * inv;
            unsigned plo = pkbf(v0, v1), phi = pkbf(v2, v3);
            *(unsigned long long*)&yrow[d0] =
                (unsigned long long)plo | ((unsigned long long)phi << 32);
        }
}

// ---------------------------------------------------------------------------
extern "C" void kernel_launch(void* const* d_in, const int* in_sizes, int n_in,
                              void* d_out, int out_size, void* d_ws, size_t ws_size,
                              hipStream_t stream)
{
    const float* x     = (const float*)d_in[0];
    const float* wqkv  = (const float*)d_in[1];
    const float* bqkv  = (const float*)d_in[2];
    const float* wproj = (const float*)d_in[3];
    const float* bproj = (const float*)d_in[4];
    float* out = (float*)d_out;

    const size_t E = (size_t)4 * 16 * 2048 * 64;
    __bf16* q      = (__bf16*)d_ws;               // E (pre-scaled)
    __bf16* k      = q + E;                       // E
    __bf16* vt     = k + E;                       // E ([B,H,64,L], k-bit-perm)
    __bf16* xb     = vt + E;                      // E
    __bf16* y      = xb;                          // alias
    __bf16* wqkvT  = xb + E;
    __bf16* wprojT = wqkvT + (size_t)3072 * 1024;

    convert_kernel<<<4096, 256, 0, stream>>>(x, xb);
    transpose_convert_kernel<<<dim3(96, 32), 256, 0, stream>>>(wqkv, wqkvT, 1024, 3072);
    transpose_convert_kernel<<<dim3(32, 32), 256, 0, stream>>>(wproj, wprojT, 1024, 1024);
    qkv_gemm_kernel<<<dim3(64, 24), 256, 0, stream>>>(xb, wqkvT, bqkv, q, k, vt);
    attn_kernel<<<dim3(32, 64), 128, 0, stream>>>(q, k, vt, y);
    proj_gemm_kernel<<<dim3(64, 8), 256, 0, stream>>>(y, wprojT, bproj, out);
}

// Round 9
// 270.684 us; speedup vs baseline: 1.0387x; 1.0387x over previous
//
#include <hip/hip_runtime.h>

// B=4, L=2048, D=1024, H=16, HD=64.
// d_in fp32: x, Wqkv, bqkv, Wproj, bproj. d_out fp32.
// Pipeline: one-time fp32->bf16 conversion, m97-style bf16 MFMA GEMMs with
// global_load_lds, and swapped-operand LDS-free causal flash attention:
// anti-diagonal pair-balanced + split-K across the block's 2 waves with an
// LDS flash-decoding merge. Zero-shuffle P pack via bit2<->3-permuted V^T.
// Attention grid is XCD-swizzled: each XCD owns 8 bh (4MB K+V = one L2).

typedef __bf16 bf16x2 __attribute__((ext_vector_type(2)));
typedef __bf16 bf16x8 __attribute__((ext_vector_type(8)));
typedef float f32x4 __attribute__((ext_vector_type(4)));
typedef float f32x16 __attribute__((ext_vector_type(16)));
typedef unsigned u32x4 __attribute__((ext_vector_type(4)));

#define MFMA16(a, b, c) __builtin_amdgcn_mfma_f32_16x16x32_bf16(a, b, c, 0, 0, 0)
#define MFMA32(a, b, c) __builtin_amdgcn_mfma_f32_32x32x16_bf16(a, b, c, 0, 0, 0)

__device__ __forceinline__ void gload_lds16(const __bf16* g, __bf16* l) {
    __builtin_amdgcn_global_load_lds(
        (const __attribute__((address_space(1))) void*)g,
        (__attribute__((address_space(3))) void*)l, 16, 0, 0);
}

__device__ __forceinline__ unsigned pkbf(float a, float b) {
    bf16x2 t = {(__bf16)a, (__bf16)b};
    return __builtin_bit_cast(unsigned, t);
}

// ---------------------------------------------------------------------------
__global__ void convert_kernel(const float* __restrict__ in, __bf16* __restrict__ out)
{
    int i = (blockIdx.x * 256 + threadIdx.x) * 8;
    f32x4 lo = *(const f32x4*)&in[i];
    f32x4 hi = *(const f32x4*)&in[i + 4];
    bf16x8 o;
#pragma unroll
    for (int j = 0; j < 4; ++j) { o[j] = (__bf16)lo[j]; o[j + 4] = (__bf16)hi[j]; }
    *(bf16x8*)&out[i] = o;
}

// ---------------------------------------------------------------------------
__global__ void transpose_convert_kernel(const float* __restrict__ in,
                                         __bf16* __restrict__ out, int R, int C)
{
    __shared__ __bf16 t[32][33];
    const int c0 = blockIdx.x * 32, r0 = blockIdx.y * 32;
    const int tx = threadIdx.x & 31, ty = threadIdx.x >> 5;
#pragma unroll
    for (int j = 0; j < 4; ++j) {
        int r = ty + j * 8;
        t[tx][r] = (__bf16)in[(size_t)(r0 + r) * C + c0 + tx];
    }
    __syncthreads();
#pragma unroll
    for (int j = 0; j < 4; ++j) {
        int r = ty + j * 8;
        out[(size_t)(c0 + r) * R + r0 + tx] = t[r][tx];
    }
}

// ---------------------------------------------------------------------------
// m97-style GEMM core (unchanged).
// ---------------------------------------------------------------------------
#define GEMM_TILE_LOOP(Abase, Bbase)                                               \
    for (int k0 = 0; k0 < 1024; k0 += 32) {                                        \
        __syncthreads();                                                           \
        _Pragma("unroll")                                                          \
        for (int i = 0; i < 2; ++i) {                                              \
            int wl = w * 2 + i;                                                    \
            int r = wl * 16 + (lane >> 2);                                         \
            int c = ((lane & 3) ^ ((r >> 1) & 3)) * 8;                             \
            gload_lds16(&Abase[(size_t)(m0 + r) * 1024 + k0 + c], &As[wl * 512]);  \
            gload_lds16(&Bbase[(size_t)(n0 + r) * 1024 + k0 + c], &Bs[wl * 512]);  \
        }                                                                          \
        __syncthreads();                                                           \
        bf16x8 af[4], bfr[4];                                                      \
        _Pragma("unroll")                                                          \
        for (int mf = 0; mf < 4; ++mf) {                                           \
            int rr = wr * 64 + mf * 16 + row;                                      \
            af[mf] = *(const bf16x8*)&As[rr * 32 + ((g ^ ((rr >> 1) & 3)) * 8)];   \
        }                                                                          \
        _Pragma("unroll")                                                          \
        for (int nf = 0; nf < 4; ++nf) {                                           \
            int rr = wc * 64 + nf * 16 + row;                                      \
            bfr[nf] = *(const bf16x8*)&Bs[rr * 32 + ((g ^ ((rr >> 1) & 3)) * 8)];  \
        }                                                                          \
        _Pragma("unroll")                                                          \
        for (int mf = 0; mf < 4; ++mf)                                             \
            _Pragma("unroll")                                                      \
            for (int nf = 0; nf < 4; ++nf)                                         \
                acc[mf][nf] = MFMA16(af[mf], bfr[nf], acc[mf][nf]);                \
    }

// QKV: q(SCALED),k -> [B,H,L,64]; v -> [B,H,64,L] with k bits 2<->3 swapped.
__global__ __launch_bounds__(256, 2)
void qkv_gemm_kernel(const __bf16* __restrict__ A, const __bf16* __restrict__ Bt,
                     const float* __restrict__ bias,
                     __bf16* __restrict__ qo, __bf16* __restrict__ ko,
                     __bf16* __restrict__ vt)
{
    __shared__ __bf16 As[128 * 32];
    __shared__ __bf16 Bs[128 * 32];
    const int tid = threadIdx.x;
    const int lane = tid & 63;
    const int w = tid >> 6;
    const int wr = w >> 1, wc = w & 1;
    const int row = lane & 15, g = lane >> 4;
    const int m0 = blockIdx.x * 128;
    const int n0 = blockIdx.y * 128;

    const f32x4 fzero = {0.f, 0.f, 0.f, 0.f};
    f32x4 acc[4][4];
#pragma unroll
    for (int a = 0; a < 4; ++a)
#pragma unroll
        for (int b = 0; b < 4; ++b) acc[a][b] = fzero;

    GEMM_TILE_LOOP(A, Bt)

    const float QSCL = 0.18033688f;   // 0.125 * log2(e)
#pragma unroll
    for (int mf = 0; mf < 4; ++mf)
#pragma unroll
        for (int nf = 0; nf < 4; ++nf) {
            int n = n0 + wc * 64 + nf * 16 + row;
            int part = n >> 10;
            int d = n & 1023;
            int h = d >> 6, hd = d & 63;
            float bv = bias[n];
#pragma unroll
            for (int i = 0; i < 4; ++i) {
                int mm = m0 + wr * 64 + mf * 16 + g * 4 + i;
                int b = mm >> 11, l = mm & 2047;
                float fv = acc[mf][nf][i] + bv;
                if (part == 0)
                    qo[(((size_t)(b * 16 + h) * 2048) + l) * 64 + hd] =
                        (__bf16)(fv * QSCL);
                else if (part == 1)
                    ko[(((size_t)(b * 16 + h) * 2048) + l) * 64 + hd] = (__bf16)fv;
                else {
                    int lp = (l & ~12) | ((l & 4) << 1) | ((l & 8) >> 1);
                    vt[(((size_t)(b * 16 + h) * 64) + hd) * 2048 + lp] = (__bf16)fv;
                }
            }
        }
}

__global__ __launch_bounds__(256, 2)
void proj_gemm_kernel(const __bf16* __restrict__ A, const __bf16* __restrict__ Bt,
                      const float* __restrict__ bias, float* __restrict__ out)
{
    __shared__ __bf16 As[128 * 32];
    __shared__ __bf16 Bs[128 * 32];
    const int tid = threadIdx.x;
    const int lane = tid & 63;
    const int w = tid >> 6;
    const int wr = w >> 1, wc = w & 1;
    const int row = lane & 15, g = lane >> 4;
    const int m0 = blockIdx.x * 128;
    const int n0 = blockIdx.y * 128;

    const f32x4 fzero = {0.f, 0.f, 0.f, 0.f};
    f32x4 acc[4][4];
#pragma unroll
    for (int a = 0; a < 4; ++a)
#pragma unroll
        for (int b = 0; b < 4; ++b) acc[a][b] = fzero;

    GEMM_TILE_LOOP(A, Bt)

#pragma unroll
    for (int mf = 0; mf < 4; ++mf)
#pragma unroll
        for (int nf = 0; nf < 4; ++nf) {
            int n = n0 + wc * 64 + nf * 16 + row;
            float bv = bias[n];
#pragma unroll
            for (int i = 0; i < 4; ++i) {
                int mm = m0 + wr * 64 + mf * 16 + g * 4 + i;
                out[(size_t)mm * 1024 + n] = acc[mf][nf][i] + bv;
            }
        }
}

// ---------------------------------------------------------------------------
// Split-K pair-balanced swapped-operand causal flash attention.
// 1D grid, 2048 blocks, 128 thr = 2 waves. XCD swizzle: with round-robin
// block->XCD dispatch (xcd = i&7), bh = (i&7)*8 + ((i>>3)&7) pins each XCD
// to 8 bh -> per-XCD K+V working set = 4MB = one L2. t = i>>6.
// Block owns q-tiles t and 63-t; wave 0 does the first half of each tile's
// k-range, wave 1 the second. LDS flash-decoding merge at the end.
// ---------------------------------------------------------------------------
__global__ __launch_bounds__(128, 2)
void attn_kernel(const __bf16* __restrict__ Qw, const __bf16* __restrict__ Kw,
                 const __bf16* __restrict__ Vt, __bf16* __restrict__ Yw)
{
    __shared__ float LmA[64], LlA[64], LOA[64][33];
    __shared__ float LmB[64], LlB[64], LOB[64][33];

    const int tid = threadIdx.x;
    const int lane = tid & 63;
    const int wv = tid >> 6;
    const int col = lane & 31;
    const int hi = lane >> 5;
    const int i0 = blockIdx.x;
    const int bh = (i0 & 7) * 8 + ((i0 >> 3) & 7);   // XCD-grouped bh
    const int t = i0 >> 6;                           // 0..31
    const int qA = t * 32;
    const int qB = (63 - t) * 32;
    const __bf16* Q = Qw + (size_t)bh * 2048 * 64;
    const __bf16* K = Kw + (size_t)bh * 2048 * 64;
    const __bf16* V = Vt + (size_t)bh * 64 * 2048;   // [64 d][2048 k] (k-perm)

    // k-range halves
    const int nA = t + 1, nB = 64 - t;
    const int hA = (nA + 1) >> 1, hB = (nB + 1) >> 1;
    const int sA = wv ? hA : 0, eA = wv ? nA : hA;
    const int sB = wv ? hB : 0, eB = wv ? nB : hB;
    const int lenA = eA - sA, lenB = eB - sB;
    const int steps = lenA > lenB ? lenA : lenB;

    bf16x8 qfA[4], qfB[4];
#pragma unroll
    for (int dc = 0; dc < 4; ++dc) {
        qfA[dc] = *(const bf16x8*)&Q[(size_t)(qA + col) * 64 + dc * 16 + hi * 8];
        qfB[dc] = *(const bf16x8*)&Q[(size_t)(qB + col) * 64 + dc * 16 + hi * 8];
    }

    f32x16 OtA[2], OtB[2];
#pragma unroll
    for (int dt = 0; dt < 2; ++dt)
#pragma unroll
        for (int i = 0; i < 16; ++i) { OtA[dt][i] = 0.f; OtB[dt][i] = 0.f; }
    float mA = -__builtin_inff(), lA = 0.f;
    float mB = -__builtin_inff(), lB = 0.f;

    auto smxpack = [&](f32x16& st, float& m, float& lsum, f32x16* Ot,
                       bool diag, bf16x8& pa0, bf16x8& pa1) {
        if (diag) {
#pragma unroll
            for (int r = 0; r < 16; ++r) {
                int crow = (r & 3) + 8 * (r >> 2) + 4 * hi;
                if (crow > col) st[r] = -1e30f;
            }
        }
        float a0 = fmaxf(fmaxf(st[0], st[1]), st[2]);
        float a1 = fmaxf(fmaxf(st[3], st[4]), st[5]);
        float a2 = fmaxf(fmaxf(st[6], st[7]), st[8]);
        float a3 = fmaxf(fmaxf(st[9], st[10]), st[11]);
        float a4 = fmaxf(st[12], st[13]);
        float a5 = fmaxf(st[14], st[15]);
        float pmax = fmaxf(fmaxf(fmaxf(a0, a1), fmaxf(a2, a3)), fmaxf(a4, a5));
        pmax = fmaxf(pmax, __shfl_xor(pmax, 32, 64));
        if (!__all(pmax - m <= 8.0f)) {
            float mnew = fmaxf(m, pmax);
            float alpha = exp2f(m - mnew);
#pragma unroll
            for (int dt = 0; dt < 2; ++dt)
#pragma unroll
                for (int i = 0; i < 16; ++i) Ot[dt][i] *= alpha;
            lsum *= alpha;
            m = mnew;
        }
#pragma unroll
        for (int r = 0; r < 16; ++r) st[r] = exp2f(st[r] - m);
        float s0 = (st[0] + st[1]) + (st[2] + st[3]);
        float s1 = (st[4] + st[5]) + (st[6] + st[7]);
        float s2 = (st[8] + st[9]) + (st[10] + st[11]);
        float s3 = (st[12] + st[13]) + (st[14] + st[15]);
        float rs = (s0 + s1) + (s2 + s3);
        rs += __shfl_xor(rs, 32, 64);
        lsum += rs;
        u32x4 w0 = {pkbf(st[0], st[1]), pkbf(st[2], st[3]),
                    pkbf(st[4], st[5]), pkbf(st[6], st[7])};
        u32x4 w1 = {pkbf(st[8], st[9]), pkbf(st[10], st[11]),
                    pkbf(st[12], st[13]), pkbf(st[14], st[15])};
        pa0 = __builtin_bit_cast(bf16x8, w0);
        pa1 = __builtin_bit_cast(bf16x8, w1);
    };

    for (int i = 0; i < steps; ++i) {
        const bool aA = i < lenA, aB = i < lenB;
        const int kbA = (sA + i) << 5, kbB = (sB + i) << 5;

        bf16x8 kfA[4], kfB[4], vfA[4], vfB[4];
        if (aA) {
#pragma unroll
            for (int dc = 0; dc < 4; ++dc)
                kfA[dc] = *(const bf16x8*)&K[(size_t)(kbA + col) * 64 + dc * 16 + hi * 8];
#pragma unroll
            for (int dt = 0; dt < 2; ++dt) {
                vfA[dt * 2 + 0] = *(const bf16x8*)&V[(size_t)(dt * 32 + col) * 2048 + kbA + hi * 8];
                vfA[dt * 2 + 1] = *(const bf16x8*)&V[(size_t)(dt * 32 + col) * 2048 + kbA + 16 + hi * 8];
            }
        }
        if (aB) {
#pragma unroll
            for (int dc = 0; dc < 4; ++dc)
                kfB[dc] = *(const bf16x8*)&K[(size_t)(kbB + col) * 64 + dc * 16 + hi * 8];
#pragma unroll
            for (int dt = 0; dt < 2; ++dt) {
                vfB[dt * 2 + 0] = *(const bf16x8*)&V[(size_t)(dt * 32 + col) * 2048 + kbB + hi * 8];
                vfB[dt * 2 + 1] = *(const bf16x8*)&V[(size_t)(dt * 32 + col) * 2048 + kbB + 16 + hi * 8];
            }
        }

        f32x16 stA, stB;
#pragma unroll
        for (int i2 = 0; i2 < 16; ++i2) { stA[i2] = 0.f; stB[i2] = 0.f; }
        __builtin_amdgcn_s_setprio(1);
#pragma unroll
        for (int dc = 0; dc < 4; ++dc) {
            if (aB) stB = MFMA32(kfB[dc], qfB[dc], stB);
            if (aA) stA = MFMA32(kfA[dc], qfA[dc], stA);
        }
        __builtin_amdgcn_s_setprio(0);

        bf16x8 paA0, paA1, paB0, paB1;
        if (aB) smxpack(stB, mB, lB, OtB, kbB == qB, paB0, paB1);
        if (aA) smxpack(stA, mA, lA, OtA, kbA == qA, paA0, paA1);

        __builtin_amdgcn_s_setprio(1);
#pragma unroll
        for (int dt = 0; dt < 2; ++dt) {
            if (aB) {
                OtB[dt] = MFMA32(vfB[dt * 2 + 0], paB0, OtB[dt]);
                OtB[dt] = MFMA32(vfB[dt * 2 + 1], paB1, OtB[dt]);
            }
            if (aA) {
                OtA[dt] = MFMA32(vfA[dt * 2 + 0], paA0, OtA[dt]);
                OtA[dt] = MFMA32(vfA[dt * 2 + 1], paA1, OtA[dt]);
            }
        }
        __builtin_amdgcn_s_setprio(0);
    }

    // ---- post partials: wave1 posts chain A, wave0 posts chain B
    if (wv == 1) {
        LmA[lane] = mA; LlA[lane] = lA;
#pragma unroll
        for (int dt = 0; dt < 2; ++dt)
#pragma unroll
            for (int r = 0; r < 16; ++r) LOA[lane][dt * 16 + r] = OtA[dt][r];
    } else {
        LmB[lane] = mB; LlB[lane] = lB;
#pragma unroll
        for (int dt = 0; dt < 2; ++dt)
#pragma unroll
            for (int r = 0; r < 16; ++r) LOB[lane][dt * 16 + r] = OtB[dt][r];
    }
    __syncthreads();

    // ---- merge + write (wave0: chain A rows; wave1: chain B rows)
    const int b = bh >> 4, h = bh & 15;
    float mo, lo_, m1, l1;
    f32x16* Oo;
    float* LOrow;
    int qrow;
    if (wv == 0) {
        mo = mA; lo_ = lA; Oo = OtA;
        m1 = LmA[lane]; l1 = LlA[lane]; LOrow = LOA[lane]; qrow = qA;
    } else {
        mo = mB; lo_ = lB; Oo = OtB;
        m1 = LmB[lane]; l1 = LlB[lane]; LOrow = LOB[lane]; qrow = qB;
    }
    float ms = fmaxf(mo, m1);
    float c0 = exp2f(mo - ms), c1 = exp2f(m1 - ms);
    float inv = 1.f / (lo_ * c0 + l1 * c1);
    __bf16* yrow = Yw + ((size_t)(b * 2048 + qrow + col)) * 1024 + h * 64;
#pragma unroll
    for (int dt = 0; dt < 2; ++dt)
#pragma unroll
        for (int rg = 0; rg < 4; ++rg) {
            int d0 = dt * 32 + rg * 8 + hi * 4;
            float v0 = (Oo[dt][rg * 4 + 0] * c0 + LOrow[dt * 16 + rg * 4 + 0] * c1) * inv;
            float v1 = (Oo[dt][rg * 4 + 1] * c0 + LOrow[dt * 16 + rg * 4 + 1] * c1) * inv;
            float v2 = (Oo[dt][rg * 4 + 2] * c0 + LOrow[dt * 16 + rg * 4 + 2] * c1) * inv;
            float v3 = (Oo[dt][rg * 4 + 3] * c0 + LOrow[dt * 16 + rg * 4 + 3] * c1) * inv;
            unsigned plo = pkbf(v0, v1), phi = pkbf(v2, v3);
            *(unsigned long long*)&yrow[d0] =
                (unsigned long long)plo | ((unsigned long long)phi << 32);
        }
}

// ---------------------------------------------------------------------------
extern "C" void kernel_launch(void* const* d_in, const int* in_sizes, int n_in,
                              void* d_out, int out_size, void* d_ws, size_t ws_size,
                              hipStream_t stream)
{
    const float* x     = (const float*)d_in[0];
    const float* wqkv  = (const float*)d_in[1];
    const float* bqkv  = (const float*)d_in[2];
    const float* wproj = (const float*)d_in[3];
    const float* bproj = (const float*)d_in[4];
    float* out = (float*)d_out;

    const size_t E = (size_t)4 * 16 * 2048 * 64;
    __bf16* q      = (__bf16*)d_ws;               // E (pre-scaled)
    __bf16* k      = q + E;                       // E
    __bf16* vt     = k + E;                       // E ([B,H,64,L], k-bit-perm)
    __bf16* xb     = vt + E;                      // E
    __bf16* y      = xb;                          // alias
    __bf16* wqkvT  = xb + E;
    __bf16* wprojT = wqkvT + (size_t)3072 * 1024;

    convert_kernel<<<4096, 256, 0, stream>>>(x, xb);
    transpose_convert_kernel<<<dim3(96, 32), 256, 0, stream>>>(wqkv, wqkvT, 1024, 3072);
    transpose_convert_kernel<<<dim3(32, 32), 256, 0, stream>>>(wproj, wprojT, 1024, 1024);
    qkv_gemm_kernel<<<dim3(64, 24), 256, 0, stream>>>(xb, wqkvT, bqkv, q, k, vt);
    attn_kernel<<<2048, 128, 0, stream>>>(q, k, vt, y);
    proj_gemm_kernel<<<dim3(64, 8), 256, 0, stream>>>(y, wprojT, bproj, out);
}

// Round 10
// 264.121 us; speedup vs baseline: 1.0645x; 1.0248x over previous
//
#include <hip/hip_runtime.h>

// B=4, L=2048, D=1024, H=16, HD=64.
// d_in fp32: x, Wqkv, bqkv, Wproj, bproj. d_out fp32.
// Pipeline: one-time fp32->bf16 conversion, m97-style bf16 MFMA GEMMs with
// global_load_lds, and swapped-operand LDS-free causal flash attention:
// anti-diagonal pair-balanced (R7 structure, shared K/V loads across chains),
// KVBLK=64 (softmax amortized over 2 k-subtiles), XCD bh-pinned grid,
// zero-shuffle P pack via bit2<->3-permuted V^T, K prefetch in-place.

typedef __bf16 bf16x2 __attribute__((ext_vector_type(2)));
typedef __bf16 bf16x8 __attribute__((ext_vector_type(8)));
typedef float f32x4 __attribute__((ext_vector_type(4)));
typedef float f32x16 __attribute__((ext_vector_type(16)));
typedef unsigned u32x4 __attribute__((ext_vector_type(4)));

#define MFMA16(a, b, c) __builtin_amdgcn_mfma_f32_16x16x32_bf16(a, b, c, 0, 0, 0)
#define MFMA32(a, b, c) __builtin_amdgcn_mfma_f32_32x32x16_bf16(a, b, c, 0, 0, 0)

__device__ __forceinline__ void gload_lds16(const __bf16* g, __bf16* l) {
    __builtin_amdgcn_global_load_lds(
        (const __attribute__((address_space(1))) void*)g,
        (__attribute__((address_space(3))) void*)l, 16, 0, 0);
}

__device__ __forceinline__ unsigned pkbf(float a, float b) {
    bf16x2 t = {(__bf16)a, (__bf16)b};
    return __builtin_bit_cast(unsigned, t);
}

// ---------------------------------------------------------------------------
__global__ void convert_kernel(const float* __restrict__ in, __bf16* __restrict__ out)
{
    int i = (blockIdx.x * 256 + threadIdx.x) * 8;
    f32x4 lo = *(const f32x4*)&in[i];
    f32x4 hi = *(const f32x4*)&in[i + 4];
    bf16x8 o;
#pragma unroll
    for (int j = 0; j < 4; ++j) { o[j] = (__bf16)lo[j]; o[j + 4] = (__bf16)hi[j]; }
    *(bf16x8*)&out[i] = o;
}

// ---------------------------------------------------------------------------
__global__ void transpose_convert_kernel(const float* __restrict__ in,
                                         __bf16* __restrict__ out, int R, int C)
{
    __shared__ __bf16 t[32][33];
    const int c0 = blockIdx.x * 32, r0 = blockIdx.y * 32;
    const int tx = threadIdx.x & 31, ty = threadIdx.x >> 5;
#pragma unroll
    for (int j = 0; j < 4; ++j) {
        int r = ty + j * 8;
        t[tx][r] = (__bf16)in[(size_t)(r0 + r) * C + c0 + tx];
    }
    __syncthreads();
#pragma unroll
    for (int j = 0; j < 4; ++j) {
        int r = ty + j * 8;
        out[(size_t)(c0 + r) * R + r0 + tx] = t[r][tx];
    }
}

// ---------------------------------------------------------------------------
// m97-style GEMM core (unchanged).
// ---------------------------------------------------------------------------
#define GEMM_TILE_LOOP(Abase, Bbase)                                               \
    for (int k0 = 0; k0 < 1024; k0 += 32) {                                        \
        __syncthreads();                                                           \
        _Pragma("unroll")                                                          \
        for (int i = 0; i < 2; ++i) {                                              \
            int wl = w * 2 + i;                                                    \
            int r = wl * 16 + (lane >> 2);                                         \
            int c = ((lane & 3) ^ ((r >> 1) & 3)) * 8;                             \
            gload_lds16(&Abase[(size_t)(m0 + r) * 1024 + k0 + c], &As[wl * 512]);  \
            gload_lds16(&Bbase[(size_t)(n0 + r) * 1024 + k0 + c], &Bs[wl * 512]);  \
        }                                                                          \
        __syncthreads();                                                           \
        bf16x8 af[4], bfr[4];                                                      \
        _Pragma("unroll")                                                          \
        for (int mf = 0; mf < 4; ++mf) {                                           \
            int rr = wr * 64 + mf * 16 + row;                                      \
            af[mf] = *(const bf16x8*)&As[rr * 32 + ((g ^ ((rr >> 1) & 3)) * 8)];   \
        }                                                                          \
        _Pragma("unroll")                                                          \
        for (int nf = 0; nf < 4; ++nf) {                                           \
            int rr = wc * 64 + nf * 16 + row;                                      \
            bfr[nf] = *(const bf16x8*)&Bs[rr * 32 + ((g ^ ((rr >> 1) & 3)) * 8)];  \
        }                                                                          \
        _Pragma("unroll")                                                          \
        for (int mf = 0; mf < 4; ++mf)                                             \
            _Pragma("unroll")                                                      \
            for (int nf = 0; nf < 4; ++nf)                                         \
                acc[mf][nf] = MFMA16(af[mf], bfr[nf], acc[mf][nf]);                \
    }

// QKV: q(SCALED),k -> [B,H,L,64]; v -> [B,H,64,L] with k bits 2<->3 swapped.
__global__ __launch_bounds__(256, 2)
void qkv_gemm_kernel(const __bf16* __restrict__ A, const __bf16* __restrict__ Bt,
                     const float* __restrict__ bias,
                     __bf16* __restrict__ qo, __bf16* __restrict__ ko,
                     __bf16* __restrict__ vt)
{
    __shared__ __bf16 As[128 * 32];
    __shared__ __bf16 Bs[128 * 32];
    const int tid = threadIdx.x;
    const int lane = tid & 63;
    const int w = tid >> 6;
    const int wr = w >> 1, wc = w & 1;
    const int row = lane & 15, g = lane >> 4;
    const int m0 = blockIdx.x * 128;
    const int n0 = blockIdx.y * 128;

    const f32x4 fzero = {0.f, 0.f, 0.f, 0.f};
    f32x4 acc[4][4];
#pragma unroll
    for (int a = 0; a < 4; ++a)
#pragma unroll
        for (int b = 0; b < 4; ++b) acc[a][b] = fzero;

    GEMM_TILE_LOOP(A, Bt)

    const float QSCL = 0.18033688f;   // 0.125 * log2(e)
#pragma unroll
    for (int mf = 0; mf < 4; ++mf)
#pragma unroll
        for (int nf = 0; nf < 4; ++nf) {
            int n = n0 + wc * 64 + nf * 16 + row;
            int part = n >> 10;
            int d = n & 1023;
            int h = d >> 6, hd = d & 63;
            float bv = bias[n];
#pragma unroll
            for (int i = 0; i < 4; ++i) {
                int mm = m0 + wr * 64 + mf * 16 + g * 4 + i;
                int b = mm >> 11, l = mm & 2047;
                float fv = acc[mf][nf][i] + bv;
                if (part == 0)
                    qo[(((size_t)(b * 16 + h) * 2048) + l) * 64 + hd] =
                        (__bf16)(fv * QSCL);
                else if (part == 1)
                    ko[(((size_t)(b * 16 + h) * 2048) + l) * 64 + hd] = (__bf16)fv;
                else {
                    int lp = (l & ~12) | ((l & 4) << 1) | ((l & 8) >> 1);
                    vt[(((size_t)(b * 16 + h) * 64) + hd) * 2048 + lp] = (__bf16)fv;
                }
            }
        }
}

__global__ __launch_bounds__(256, 2)
void proj_gemm_kernel(const __bf16* __restrict__ A, const __bf16* __restrict__ Bt,
                      const float* __restrict__ bias, float* __restrict__ out)
{
    __shared__ __bf16 As[128 * 32];
    __shared__ __bf16 Bs[128 * 32];
    const int tid = threadIdx.x;
    const int lane = tid & 63;
    const int w = tid >> 6;
    const int wr = w >> 1, wc = w & 1;
    const int row = lane & 15, g = lane >> 4;
    const int m0 = blockIdx.x * 128;
    const int n0 = blockIdx.y * 128;

    const f32x4 fzero = {0.f, 0.f, 0.f, 0.f};
    f32x4 acc[4][4];
#pragma unroll
    for (int a = 0; a < 4; ++a)
#pragma unroll
        for (int b = 0; b < 4; ++b) acc[a][b] = fzero;

    GEMM_TILE_LOOP(A, Bt)

#pragma unroll
    for (int mf = 0; mf < 4; ++mf)
#pragma unroll
        for (int nf = 0; nf < 4; ++nf) {
            int n = n0 + wc * 64 + nf * 16 + row;
            float bv = bias[n];
#pragma unroll
            for (int i = 0; i < 4; ++i) {
                int mm = m0 + wr * 64 + mf * 16 + g * 4 + i;
                out[(size_t)mm * 1024 + n] = acc[mf][nf][i] + bv;
            }
        }
}

// ---------------------------------------------------------------------------
// Pair-balanced swapped-operand causal flash attention, KVBLK=64.
// 1D grid 1024 blocks, 128 thr = 2 waves. XCD pin: bh = (i&7)*8 + ((i>>3)&7)
// (each XCD owns 8 bh -> 4MB K+V = one L2). Wave wv owns q-tiles
// t = 2*(i>>6)+wv and 63-t; both chains share each step's K/V tile loads.
// Each step covers 64 keys (2 subtiles of 32); softmax/pack amortized.
// ---------------------------------------------------------------------------
__global__ __launch_bounds__(128, 2)
void attn_kernel(const __bf16* __restrict__ Qw, const __bf16* __restrict__ Kw,
                 const __bf16* __restrict__ Vt, __bf16* __restrict__ Yw)
{
    const int tid = threadIdx.x;
    const int lane = tid & 63;
    const int wv = tid >> 6;
    const int col = lane & 31;
    const int hi = lane >> 5;
    const int i0 = blockIdx.x;
    const int bh = (i0 & 7) * 8 + ((i0 >> 3) & 7);
    const int t = (i0 >> 6) * 2 + wv;          // 0..31
    const int qA = t * 32;
    const int qB = (63 - t) * 32;
    const __bf16* Q = Qw + (size_t)bh * 2048 * 64;
    const __bf16* K = Kw + (size_t)bh * 2048 * 64;
    const __bf16* V = Vt + (size_t)bh * 64 * 2048;   // [64 d][2048 k] (k-perm)

    bf16x8 qfA[4], qfB[4];
#pragma unroll
    for (int dc = 0; dc < 4; ++dc) {
        qfA[dc] = *(const bf16x8*)&Q[(size_t)(qA + col) * 64 + dc * 16 + hi * 8];
        qfB[dc] = *(const bf16x8*)&Q[(size_t)(qB + col) * 64 + dc * 16 + hi * 8];
    }

    f32x16 OtA[2], OtB[2];
#pragma unroll
    for (int dt = 0; dt < 2; ++dt)
#pragma unroll
        for (int i = 0; i < 16; ++i) { OtA[dt][i] = 0.f; OtB[dt][i] = 0.f; }
    float mA = -__builtin_inff(), lA = 0.f;
    float mB = -__builtin_inff(), lB = 0.f;

    // 64-key softmax+pack; s1/act1 optional second subtile. exp2 domain.
    auto smx64 = [&](f32x16& s0, f32x16& s1, bool act1, bool dg0, bool dg1,
                     float& m, float& lsum, f32x16* Ot,
                     bf16x8& p0, bf16x8& p1, bf16x8& p2, bf16x8& p3) {
        if (dg0) {
#pragma unroll
            for (int r = 0; r < 16; ++r) {
                int crow = (r & 3) + 8 * (r >> 2) + 4 * hi;
                if (crow > col) s0[r] = -1e30f;
            }
        }
        if (act1 && dg1) {
#pragma unroll
            for (int r = 0; r < 16; ++r) {
                int crow = (r & 3) + 8 * (r >> 2) + 4 * hi;
                if (crow > col) s1[r] = -1e30f;
            }
        }
        float a0 = fmaxf(fmaxf(s0[0], s0[1]), fmaxf(s0[2], s0[3]));
        float a1 = fmaxf(fmaxf(s0[4], s0[5]), fmaxf(s0[6], s0[7]));
        float a2 = fmaxf(fmaxf(s0[8], s0[9]), fmaxf(s0[10], s0[11]));
        float a3 = fmaxf(fmaxf(s0[12], s0[13]), fmaxf(s0[14], s0[15]));
        float pmax = fmaxf(fmaxf(a0, a1), fmaxf(a2, a3));
        if (act1) {
            float b0 = fmaxf(fmaxf(s1[0], s1[1]), fmaxf(s1[2], s1[3]));
            float b1 = fmaxf(fmaxf(s1[4], s1[5]), fmaxf(s1[6], s1[7]));
            float b2 = fmaxf(fmaxf(s1[8], s1[9]), fmaxf(s1[10], s1[11]));
            float b3 = fmaxf(fmaxf(s1[12], s1[13]), fmaxf(s1[14], s1[15]));
            pmax = fmaxf(pmax, fmaxf(fmaxf(b0, b1), fmaxf(b2, b3)));
        }
        pmax = fmaxf(pmax, __shfl_xor(pmax, 32, 64));
        if (!__all(pmax - m <= 8.0f)) {
            float mnew = fmaxf(m, pmax);
            float alpha = exp2f(m - mnew);
#pragma unroll
            for (int dt = 0; dt < 2; ++dt)
#pragma unroll
                for (int i = 0; i < 16; ++i) Ot[dt][i] *= alpha;
            lsum *= alpha;
            m = mnew;
        }
#pragma unroll
        for (int r = 0; r < 16; ++r) s0[r] = exp2f(s0[r] - m);
        float rs = ((s0[0] + s0[1]) + (s0[2] + s0[3])) + ((s0[4] + s0[5]) + (s0[6] + s0[7]))
                 + ((s0[8] + s0[9]) + (s0[10] + s0[11])) + ((s0[12] + s0[13]) + (s0[14] + s0[15]));
        if (act1) {
#pragma unroll
            for (int r = 0; r < 16; ++r) s1[r] = exp2f(s1[r] - m);
            rs += ((s1[0] + s1[1]) + (s1[2] + s1[3])) + ((s1[4] + s1[5]) + (s1[6] + s1[7]))
                + ((s1[8] + s1[9]) + (s1[10] + s1[11])) + ((s1[12] + s1[13]) + (s1[14] + s1[15]));
        }
        rs += __shfl_xor(rs, 32, 64);
        lsum += rs;
        u32x4 w0 = {pkbf(s0[0], s0[1]), pkbf(s0[2], s0[3]),
                    pkbf(s0[4], s0[5]), pkbf(s0[6], s0[7])};
        u32x4 w1 = {pkbf(s0[8], s0[9]), pkbf(s0[10], s0[11]),
                    pkbf(s0[12], s0[13]), pkbf(s0[14], s0[15])};
        p0 = __builtin_bit_cast(bf16x8, w0);
        p1 = __builtin_bit_cast(bf16x8, w1);
        if (act1) {
            u32x4 w2 = {pkbf(s1[0], s1[1]), pkbf(s1[2], s1[3]),
                        pkbf(s1[4], s1[5]), pkbf(s1[6], s1[7])};
            u32x4 w3 = {pkbf(s1[8], s1[9]), pkbf(s1[10], s1[11]),
                        pkbf(s1[12], s1[13]), pkbf(s1[14], s1[15])};
            p2 = __builtin_bit_cast(bf16x8, w2);
            p3 = __builtin_bit_cast(bf16x8, w3);
        }
    };

    const int nsteps = (64 - t + 1) >> 1;   // ceil((64-t)/2)

    // prologue: K tiles for step 0 (kb=0, kb=32; both ≤ qB since qB ≥ 1024)
    bf16x8 kf0[4], kf1[4];
#pragma unroll
    for (int dc = 0; dc < 4; ++dc) {
        kf0[dc] = *(const bf16x8*)&K[(size_t)col * 64 + dc * 16 + hi * 8];
        kf1[dc] = *(const bf16x8*)&K[(size_t)(32 + col) * 64 + dc * 16 + hi * 8];
    }

    for (int u = 0; u < nsteps; ++u) {
        const int kb = u << 6;
        const bool actB1 = (kb + 32 <= qB);
        const bool actA0 = (kb <= qA);
        const bool actA1 = (kb + 32 <= qA);

        // V loads for the current 64 keys (shared by both chains)
        bf16x8 v00, v01, v02, v03, v10, v11, v12, v13;
        {
            const __bf16* vb0 = &V[(size_t)col * 2048 + kb];
            const __bf16* vb1 = &V[(size_t)(32 + col) * 2048 + kb];
            v00 = *(const bf16x8*)&vb0[hi * 8];
            v01 = *(const bf16x8*)&vb0[16 + hi * 8];
            v02 = *(const bf16x8*)&vb1[hi * 8];
            v03 = *(const bf16x8*)&vb1[16 + hi * 8];
            if (actB1) {
                v10 = *(const bf16x8*)&vb0[32 + hi * 8];
                v11 = *(const bf16x8*)&vb0[48 + hi * 8];
                v12 = *(const bf16x8*)&vb1[32 + hi * 8];
                v13 = *(const bf16x8*)&vb1[48 + hi * 8];
            }
        }

        // QK^T for both subtiles, both chains
        f32x16 stB0, stB1, stA0, stA1;
#pragma unroll
        for (int i = 0; i < 16; ++i) { stB0[i] = 0.f; stB1[i] = 0.f; stA0[i] = 0.f; stA1[i] = 0.f; }
        __builtin_amdgcn_s_setprio(1);
#pragma unroll
        for (int dc = 0; dc < 4; ++dc) stB0 = MFMA32(kf0[dc], qfB[dc], stB0);
        if (actB1) {
#pragma unroll
            for (int dc = 0; dc < 4; ++dc) stB1 = MFMA32(kf1[dc], qfB[dc], stB1);
        }
        if (actA0) {
#pragma unroll
            for (int dc = 0; dc < 4; ++dc) stA0 = MFMA32(kf0[dc], qfA[dc], stA0);
        }
        if (actA1) {
#pragma unroll
            for (int dc = 0; dc < 4; ++dc) stA1 = MFMA32(kf1[dc], qfA[dc], stA1);
        }
        __builtin_amdgcn_s_setprio(0);

        // prefetch next step's K tiles in-place (clamped; unused on last iter)
        {
            int kn = kb + 64;  if (kn > qB) kn = qB;
            int kn1 = kn + 32; if (kn1 > qB) kn1 = qB;
#pragma unroll
            for (int dc = 0; dc < 4; ++dc) {
                kf0[dc] = *(const bf16x8*)&K[(size_t)(kn + col) * 64 + dc * 16 + hi * 8];
                kf1[dc] = *(const bf16x8*)&K[(size_t)(kn1 + col) * 64 + dc * 16 + hi * 8];
            }
        }

        // softmax + pack
        bf16x8 pB0, pB1, pB2, pB3, pA0, pA1, pA2, pA3;
        smx64(stB0, stB1, actB1, kb == qB, kb + 32 == qB, mB, lB, OtB,
              pB0, pB1, pB2, pB3);
        if (actA0)
            smx64(stA0, stA1, actA1, kb == qA, kb + 32 == qA, mA, lA, OtA,
                  pA0, pA1, pA2, pA3);

        // PV
        __builtin_amdgcn_s_setprio(1);
        OtB[0] = MFMA32(v00, pB0, OtB[0]);
        OtB[0] = MFMA32(v01, pB1, OtB[0]);
        OtB[1] = MFMA32(v02, pB0, OtB[1]);
        OtB[1] = MFMA32(v03, pB1, OtB[1]);
        if (actB1) {
            OtB[0] = MFMA32(v10, pB2, OtB[0]);
            OtB[0] = MFMA32(v11, pB3, OtB[0]);
            OtB[1] = MFMA32(v12, pB2, OtB[1]);
            OtB[1] = MFMA32(v13, pB3, OtB[1]);
        }
        if (actA0) {
            OtA[0] = MFMA32(v00, pA0, OtA[0]);
            OtA[0] = MFMA32(v01, pA1, OtA[0]);
            OtA[1] = MFMA32(v02, pA0, OtA[1]);
            OtA[1] = MFMA32(v03, pA1, OtA[1]);
        }
        if (actA1) {
            OtA[0] = MFMA32(v10, pA2, OtA[0]);
            OtA[0] = MFMA32(v11, pA3, OtA[0]);
            OtA[1] = MFMA32(v12, pA2, OtA[1]);
            OtA[1] = MFMA32(v13, pA3, OtA[1]);
        }
        __builtin_amdgcn_s_setprio(0);
    }

    // ---- epilogue: O^T C-layout col=q(lane-local), d = dt*32+8*(r>>2)+4*hi+(r&3)
    const int b = bh >> 4, h = bh & 15;
    const float invA = 1.f / lA, invB = 1.f / lB;
    __bf16* yrowA = Yw + ((size_t)(b * 2048 + qA + col)) * 1024 + h * 64;
    __bf16* yrowB = Yw + ((size_t)(b * 2048 + qB + col)) * 1024 + h * 64;
#pragma unroll
    for (int dt = 0; dt < 2; ++dt)
#pragma unroll
        for (int rg = 0; rg < 4; ++rg) {
            int d0 = dt * 32 + rg * 8 + hi * 4;
            unsigned lo = pkbf(OtA[dt][rg * 4 + 0] * invA, OtA[dt][rg * 4 + 1] * invA);
            unsigned h2 = pkbf(OtA[dt][rg * 4 + 2] * invA, OtA[dt][rg * 4 + 3] * invA);
            *(unsigned long long*)&yrowA[d0] =
                (unsigned long long)lo | ((unsigned long long)h2 << 32);
            lo = pkbf(OtB[dt][rg * 4 + 0] * invB, OtB[dt][rg * 4 + 1] * invB);
            h2 = pkbf(OtB[dt][rg * 4 + 2] * invB, OtB[dt][rg * 4 + 3] * invB);
            *(unsigned long long*)&yrowB[d0] =
                (unsigned long long)lo | ((unsigned long long)h2 << 32);
        }
}

// ---------------------------------------------------------------------------
extern "C" void kernel_launch(void* const* d_in, const int* in_sizes, int n_in,
                              void* d_out, int out_size, void* d_ws, size_t ws_size,
                              hipStream_t stream)
{
    const float* x     = (const float*)d_in[0];
    const float* wqkv  = (const float*)d_in[1];
    const float* bqkv  = (const float*)d_in[2];
    const float* wproj = (const float*)d_in[3];
    const float* bproj = (const float*)d_in[4];
    float* out = (float*)d_out;

    const size_t E = (size_t)4 * 16 * 2048 * 64;
    __bf16* q      = (__bf16*)d_ws;               // E (pre-scaled)
    __bf16* k      = q + E;                       // E
    __bf16* vt     = k + E;                       // E ([B,H,64,L], k-bit-perm)
    __bf16* xb     = vt + E;                      // E
    __bf16* y      = xb;                          // alias
    __bf16* wqkvT  = xb + E;
    __bf16* wprojT = wqkvT + (size_t)3072 * 1024;

    convert_kernel<<<4096, 256, 0, stream>>>(x, xb);
    transpose_convert_kernel<<<dim3(96, 32), 256, 0, stream>>>(wqkv, wqkvT, 1024, 3072);
    transpose_convert_kernel<<<dim3(32, 32), 256, 0, stream>>>(wproj, wprojT, 1024, 1024);
    qkv_gemm_kernel<<<dim3(64, 24), 256, 0, stream>>>(xb, wqkvT, bqkv, q, k, vt);
    attn_kernel<<<1024, 128, 0, stream>>>(q, k, vt, y);
    proj_gemm_kernel<<<dim3(64, 8), 256, 0, stream>>>(y, wprojT, bproj, out);
}

// Round 11
// 184.355 us; speedup vs baseline: 1.5251x; 1.4327x over previous
//
#include <hip/hip_runtime.h>

// B=4, L=2048, D=1024, H=16, HD=64.
// d_in fp32: x, Wqkv, bqkv, Wproj, bproj. d_out fp32.
// Pipeline: fp32->bf16 converts, m97-style bf16 MFMA GEMMs (global_load_lds),
// swapped-operand LDS-free causal flash attention (R7 dual-chain structure)
// with LANE-MAJOR TILED Q/K/V layouts so every fragment load is a coalesced
// base+lane*16 read (8 cache lines/instr instead of 32-64). XCD bh-pinned.
//
// Q2/K2 layout (bf16): addr(bh,l,hd) = ((bh*64 + (l>>5))*4 + (hd>>4))*512
//                                      + ((hd>>3)&1)*256 + (l&31)*8 + (hd&7)
// V2 layout (bf16):    addr(bh,l,hd) = ((bh*64 + (l>>5))*4 + (hd>>5)*2
//                                      + ((l>>4)&1))*512 + ((l>>2)&1)*256
//                                      + (hd&31)*8 + ((l&3)|(((l>>3)&1)<<2))
// (V2 bakes in the PV k-placement k4 = (j&3)+8*(j>>2)+4*hi.)

typedef __bf16 bf16x2 __attribute__((ext_vector_type(2)));
typedef __bf16 bf16x8 __attribute__((ext_vector_type(8)));
typedef float f32x4 __attribute__((ext_vector_type(4)));
typedef float f32x16 __attribute__((ext_vector_type(16)));
typedef unsigned u32x4 __attribute__((ext_vector_type(4)));

#define MFMA16(a, b, c) __builtin_amdgcn_mfma_f32_16x16x32_bf16(a, b, c, 0, 0, 0)
#define MFMA32(a, b, c) __builtin_amdgcn_mfma_f32_32x32x16_bf16(a, b, c, 0, 0, 0)

__device__ __forceinline__ void gload_lds16(const __bf16* g, __bf16* l) {
    __builtin_amdgcn_global_load_lds(
        (const __attribute__((address_space(1))) void*)g,
        (__attribute__((address_space(3))) void*)l, 16, 0, 0);
}

__device__ __forceinline__ unsigned pkbf(float a, float b) {
    bf16x2 t = {(__bf16)a, (__bf16)b};
    return __builtin_bit_cast(unsigned, t);
}

// ---------------------------------------------------------------------------
__global__ void convert_kernel(const float* __restrict__ in, __bf16* __restrict__ out)
{
    int i = (blockIdx.x * 256 + threadIdx.x) * 8;
    f32x4 lo = *(const f32x4*)&in[i];
    f32x4 hi = *(const f32x4*)&in[i + 4];
    bf16x8 o;
#pragma unroll
    for (int j = 0; j < 4; ++j) { o[j] = (__bf16)lo[j]; o[j + 4] = (__bf16)hi[j]; }
    *(bf16x8*)&out[i] = o;
}

// ---------------------------------------------------------------------------
__global__ void transpose_convert_kernel(const float* __restrict__ in,
                                         __bf16* __restrict__ out, int R, int C)
{
    __shared__ __bf16 t[32][33];
    const int c0 = blockIdx.x * 32, r0 = blockIdx.y * 32;
    const int tx = threadIdx.x & 31, ty = threadIdx.x >> 5;
#pragma unroll
    for (int j = 0; j < 4; ++j) {
        int r = ty + j * 8;
        t[tx][r] = (__bf16)in[(size_t)(r0 + r) * C + c0 + tx];
    }
    __syncthreads();
#pragma unroll
    for (int j = 0; j < 4; ++j) {
        int r = ty + j * 8;
        out[(size_t)(c0 + r) * R + r0 + tx] = t[r][tx];
    }
}

// ---------------------------------------------------------------------------
// m97-style GEMM core (unchanged).
// ---------------------------------------------------------------------------
#define GEMM_TILE_LOOP(Abase, Bbase)                                               \
    for (int k0 = 0; k0 < 1024; k0 += 32) {                                        \
        __syncthreads();                                                           \
        _Pragma("unroll")                                                          \
        for (int i = 0; i < 2; ++i) {                                              \
            int wl = w * 2 + i;                                                    \
            int r = wl * 16 + (lane >> 2);                                         \
            int c = ((lane & 3) ^ ((r >> 1) & 3)) * 8;                             \
            gload_lds16(&Abase[(size_t)(m0 + r) * 1024 + k0 + c], &As[wl * 512]);  \
            gload_lds16(&Bbase[(size_t)(n0 + r) * 1024 + k0 + c], &Bs[wl * 512]);  \
        }                                                                          \
        __syncthreads();                                                           \
        bf16x8 af[4], bfr[4];                                                      \
        _Pragma("unroll")                                                          \
        for (int mf = 0; mf < 4; ++mf) {                                           \
            int rr = wr * 64 + mf * 16 + row;                                      \
            af[mf] = *(const bf16x8*)&As[rr * 32 + ((g ^ ((rr >> 1) & 3)) * 8)];   \
        }                                                                          \
        _Pragma("unroll")                                                          \
        for (int nf = 0; nf < 4; ++nf) {                                           \
            int rr = wc * 64 + nf * 16 + row;                                      \
            bfr[nf] = *(const bf16x8*)&Bs[rr * 32 + ((g ^ ((rr >> 1) & 3)) * 8)];  \
        }                                                                          \
        _Pragma("unroll")                                                          \
        for (int mf = 0; mf < 4; ++mf)                                             \
            _Pragma("unroll")                                                      \
            for (int nf = 0; nf < 4; ++nf)                                         \
                acc[mf][nf] = MFMA16(af[mf], bfr[nf], acc[mf][nf]);                \
    }

// QKV GEMM. Epilogue scatters into lane-major tiled Q2(scaled)/K2/V2.
__global__ __launch_bounds__(256, 2)
void qkv_gemm_kernel(const __bf16* __restrict__ A, const __bf16* __restrict__ Bt,
                     const float* __restrict__ bias,
                     __bf16* __restrict__ q2, __bf16* __restrict__ k2,
                     __bf16* __restrict__ v2)
{
    __shared__ __bf16 As[128 * 32];
    __shared__ __bf16 Bs[128 * 32];
    const int tid = threadIdx.x;
    const int lane = tid & 63;
    const int w = tid >> 6;
    const int wr = w >> 1, wc = w & 1;
    const int row = lane & 15, g = lane >> 4;
    const int m0 = blockIdx.x * 128;
    const int n0 = blockIdx.y * 128;

    const f32x4 fzero = {0.f, 0.f, 0.f, 0.f};
    f32x4 acc[4][4];
#pragma unroll
    for (int a = 0; a < 4; ++a)
#pragma unroll
        for (int b = 0; b < 4; ++b) acc[a][b] = fzero;

    GEMM_TILE_LOOP(A, Bt)

    const float QSCL = 0.18033688f;   // 0.125 * log2(e)
#pragma unroll
    for (int mf = 0; mf < 4; ++mf)
#pragma unroll
        for (int nf = 0; nf < 4; ++nf) {
            int n = n0 + wc * 64 + nf * 16 + row;
            int part = n >> 10;
            int d = n & 1023;
            int h = d >> 6, hd = d & 63;
            float bv = bias[n];
#pragma unroll
            for (int i = 0; i < 4; ++i) {
                int mm = m0 + wr * 64 + mf * 16 + g * 4 + i;
                int b = mm >> 11, l = mm & 2047;
                size_t bh64 = (size_t)(b * 16 + h) * 64;
                float fv = acc[mf][nf][i] + bv;
                if (part == 2) {
                    size_t addr = ((bh64 + (l >> 5)) * 4 + (hd >> 5) * 2 +
                                   ((l >> 4) & 1)) * 512 +
                                  ((l >> 2) & 1) * 256 + (hd & 31) * 8 +
                                  ((l & 3) | (((l >> 3) & 1) << 2));
                    v2[addr] = (__bf16)fv;
                } else {
                    size_t addr = ((bh64 + (l >> 5)) * 4 + (hd >> 4)) * 512 +
                                  ((hd >> 3) & 1) * 256 + (l & 31) * 8 + (hd & 7);
                    if (part == 0) q2[addr] = (__bf16)(fv * QSCL);
                    else           k2[addr] = (__bf16)fv;
                }
            }
        }
}

__global__ __launch_bounds__(256, 2)
void proj_gemm_kernel(const __bf16* __restrict__ A, const __bf16* __restrict__ Bt,
                      const float* __restrict__ bias, float* __restrict__ out)
{
    __shared__ __bf16 As[128 * 32];
    __shared__ __bf16 Bs[128 * 32];
    const int tid = threadIdx.x;
    const int lane = tid & 63;
    const int w = tid >> 6;
    const int wr = w >> 1, wc = w & 1;
    const int row = lane & 15, g = lane >> 4;
    const int m0 = blockIdx.x * 128;
    const int n0 = blockIdx.y * 128;

    const f32x4 fzero = {0.f, 0.f, 0.f, 0.f};
    f32x4 acc[4][4];
#pragma unroll
    for (int a = 0; a < 4; ++a)
#pragma unroll
        for (int b = 0; b < 4; ++b) acc[a][b] = fzero;

    GEMM_TILE_LOOP(A, Bt)

#pragma unroll
    for (int mf = 0; mf < 4; ++mf)
#pragma unroll
        for (int nf = 0; nf < 4; ++nf) {
            int n = n0 + wc * 64 + nf * 16 + row;
            float bv = bias[n];
#pragma unroll
            for (int i = 0; i < 4; ++i) {
                int mm = m0 + wr * 64 + mf * 16 + g * 4 + i;
                out[(size_t)mm * 1024 + n] = acc[mf][nf][i] + bv;
            }
        }
}

// ---------------------------------------------------------------------------
// Pair-balanced swapped-operand causal flash attention (R7 structure),
// lane-major tiled Q2/K2/V2 -> every load is base+lane*16 (coalesced).
// 1D grid 1024 blocks, 128 thr = 2 waves. XCD pin: bh = (i&7)*8+((i>>3)&7).
// Wave wv owns q-tiles t = 2*(i>>6)+wv and 63-t (65 k-tile units each).
// ---------------------------------------------------------------------------
__global__ __launch_bounds__(128, 2)
void attn_kernel(const __bf16* __restrict__ Q2, const __bf16* __restrict__ K2,
                 const __bf16* __restrict__ V2, __bf16* __restrict__ Yw)
{
    const int tid = threadIdx.x;
    const int lane = tid & 63;
    const int wv = tid >> 6;
    const int col = lane & 31;
    const int hi = lane >> 5;
    const int i0 = blockIdx.x;
    const int bh = (i0 & 7) * 8 + ((i0 >> 3) & 7);
    const int t = (i0 >> 6) * 2 + wv;          // 0..31
    const int qA = t * 32;
    const int qB = (63 - t) * 32;
    const size_t tb = (size_t)bh * 64;         // tile base

    // Q fragments (coalesced: base + lane*16)
    bf16x8 qfA[4], qfB[4];
#pragma unroll
    for (int dc = 0; dc < 4; ++dc) {
        qfA[dc] = *(const bf16x8*)&Q2[((tb + t) * 4 + dc) * 512 + lane * 8];
        qfB[dc] = *(const bf16x8*)&Q2[((tb + 63 - t) * 4 + dc) * 512 + lane * 8];
    }

    f32x16 OtA[2], OtB[2];
#pragma unroll
    for (int dt = 0; dt < 2; ++dt)
#pragma unroll
        for (int i = 0; i < 16; ++i) { OtA[dt][i] = 0.f; OtB[dt][i] = 0.f; }
    float mA = -__builtin_inff(), lA = 0.f;
    float mB = -__builtin_inff(), lB = 0.f;

    auto smxpack = [&](f32x16& st, float& m, float& lsum, f32x16* Ot,
                       bool diag, bf16x8& pa0, bf16x8& pa1) {
        if (diag) {
#pragma unroll
            for (int r = 0; r < 16; ++r) {
                int crow = (r & 3) + 8 * (r >> 2) + 4 * hi;
                if (crow > col) st[r] = -1e30f;
            }
        }
        float a0 = fmaxf(fmaxf(st[0], st[1]), st[2]);
        float a1 = fmaxf(fmaxf(st[3], st[4]), st[5]);
        float a2 = fmaxf(fmaxf(st[6], st[7]), st[8]);
        float a3 = fmaxf(fmaxf(st[9], st[10]), st[11]);
        float a4 = fmaxf(st[12], st[13]);
        float a5 = fmaxf(st[14], st[15]);
        float pmax = fmaxf(fmaxf(fmaxf(a0, a1), fmaxf(a2, a3)), fmaxf(a4, a5));
        pmax = fmaxf(pmax, __shfl_xor(pmax, 32, 64));
        if (!__all(pmax - m <= 8.0f)) {
            float mnew = fmaxf(m, pmax);
            float alpha = exp2f(m - mnew);
#pragma unroll
            for (int dt = 0; dt < 2; ++dt)
#pragma unroll
                for (int i = 0; i < 16; ++i) Ot[dt][i] *= alpha;
            lsum *= alpha;
            m = mnew;
        }
#pragma unroll
        for (int r = 0; r < 16; ++r) st[r] = exp2f(st[r] - m);
        float s0 = (st[0] + st[1]) + (st[2] + st[3]);
        float s1 = (st[4] + st[5]) + (st[6] + st[7]);
        float s2 = (st[8] + st[9]) + (st[10] + st[11]);
        float s3 = (st[12] + st[13]) + (st[14] + st[15]);
        float rs = (s0 + s1) + (s2 + s3);
        rs += __shfl_xor(rs, 32, 64);
        lsum += rs;
        u32x4 w0 = {pkbf(st[0], st[1]), pkbf(st[2], st[3]),
                    pkbf(st[4], st[5]), pkbf(st[6], st[7])};
        u32x4 w1 = {pkbf(st[8], st[9]), pkbf(st[10], st[11]),
                    pkbf(st[12], st[13]), pkbf(st[14], st[15])};
        pa0 = __builtin_bit_cast(bf16x8, w0);
        pa1 = __builtin_bit_cast(bf16x8, w1);
    };

    // preload K tile 0 (coalesced)
    bf16x8 kf[4];
#pragma unroll
    for (int dc = 0; dc < 4; ++dc)
        kf[dc] = *(const bf16x8*)&K2[(tb * 4 + dc) * 512 + lane * 8];

    for (int kb = 0; kb <= qB; kb += 32) {
        const int kt = kb >> 5;
        const bool dual = (kb <= qA);
        // V loads for this tile (coalesced; consumed after softmax)
        bf16x8 vf[4];
#pragma unroll
        for (int dt = 0; dt < 2; ++dt)
#pragma unroll
            for (int half = 0; half < 2; ++half)
                vf[dt * 2 + half] = *(const bf16x8*)
                    &V2[((tb + kt) * 4 + dt * 2 + half) * 512 + lane * 8];

        f32x16 stA, stB;
#pragma unroll
        for (int i = 0; i < 16; ++i) { stA[i] = 0.f; stB[i] = 0.f; }
        __builtin_amdgcn_s_setprio(1);
        if (dual) {
#pragma unroll
            for (int dc = 0; dc < 4; ++dc) {
                stB = MFMA32(kf[dc], qfB[dc], stB);
                stA = MFMA32(kf[dc], qfA[dc], stA);
            }
        } else {
#pragma unroll
            for (int dc = 0; dc < 4; ++dc)
                stB = MFMA32(kf[dc], qfB[dc], stB);
        }
        __builtin_amdgcn_s_setprio(0);

        // prefetch next K tile (clamped; unused on last iteration)
        const int ktn = (kb + 32 <= qB) ? kt + 1 : kt;
        bf16x8 kfn[4];
#pragma unroll
        for (int dc = 0; dc < 4; ++dc)
            kfn[dc] = *(const bf16x8*)&K2[((tb + ktn) * 4 + dc) * 512 + lane * 8];

        bf16x8 paA0, paA1, paB0, paB1;
        smxpack(stB, mB, lB, OtB, kb == qB, paB0, paB1);
        if (dual) smxpack(stA, mA, lA, OtA, kb == qA, paA0, paA1);

        __builtin_amdgcn_s_setprio(1);
#pragma unroll
        for (int dt = 0; dt < 2; ++dt) {
            OtB[dt] = MFMA32(vf[dt * 2 + 0], paB0, OtB[dt]);
            OtB[dt] = MFMA32(vf[dt * 2 + 1], paB1, OtB[dt]);
            if (dual) {
                OtA[dt] = MFMA32(vf[dt * 2 + 0], paA0, OtA[dt]);
                OtA[dt] = MFMA32(vf[dt * 2 + 1], paA1, OtA[dt]);
            }
        }
        __builtin_amdgcn_s_setprio(0);

#pragma unroll
        for (int dc = 0; dc < 4; ++dc) kf[dc] = kfn[dc];
    }

    // ---- epilogue: O^T C-layout col=q(lane-local), d = dt*32+8*(r>>2)+4*hi+(r&3)
    const int b = bh >> 4, h = bh & 15;
    const float invA = 1.f / lA, invB = 1.f / lB;
    __bf16* yrowA = Yw + ((size_t)(b * 2048 + qA + col)) * 1024 + h * 64;
    __bf16* yrowB = Yw + ((size_t)(b * 2048 + qB + col)) * 1024 + h * 64;
#pragma unroll
    for (int dt = 0; dt < 2; ++dt)
#pragma unroll
        for (int rg = 0; rg < 4; ++rg) {
            int d0 = dt * 32 + rg * 8 + hi * 4;
            unsigned lo = pkbf(OtA[dt][rg * 4 + 0] * invA, OtA[dt][rg * 4 + 1] * invA);
            unsigned h2 = pkbf(OtA[dt][rg * 4 + 2] * invA, OtA[dt][rg * 4 + 3] * invA);
            *(unsigned long long*)&yrowA[d0] =
                (unsigned long long)lo | ((unsigned long long)h2 << 32);
            lo = pkbf(OtB[dt][rg * 4 + 0] * invB, OtB[dt][rg * 4 + 1] * invB);
            h2 = pkbf(OtB[dt][rg * 4 + 2] * invB, OtB[dt][rg * 4 + 3] * invB);
            *(unsigned long long*)&yrowB[d0] =
                (unsigned long long)lo | ((unsigned long long)h2 << 32);
        }
}

// ---------------------------------------------------------------------------
extern "C" void kernel_launch(void* const* d_in, const int* in_sizes, int n_in,
                              void* d_out, int out_size, void* d_ws, size_t ws_size,
                              hipStream_t stream)
{
    const float* x     = (const float*)d_in[0];
    const float* wqkv  = (const float*)d_in[1];
    const float* bqkv  = (const float*)d_in[2];
    const float* wproj = (const float*)d_in[3];
    const float* bproj = (const float*)d_in[4];
    float* out = (float*)d_out;

    const size_t E = (size_t)4 * 16 * 2048 * 64;
    __bf16* q2     = (__bf16*)d_ws;               // E (pre-scaled, tiled)
    __bf16* k2     = q2 + E;                      // E (tiled)
    __bf16* v2     = k2 + E;                      // E (tiled, PV k-placement)
    __bf16* xb     = v2 + E;                      // E
    __bf16* y      = xb;                          // alias
    __bf16* wqkvT  = xb + E;
    __bf16* wprojT = wqkvT + (size_t)3072 * 1024;

    convert_kernel<<<4096, 256, 0, stream>>>(x, xb);
    transpose_convert_kernel<<<dim3(96, 32), 256, 0, stream>>>(wqkv, wqkvT, 1024, 3072);
    transpose_convert_kernel<<<dim3(32, 32), 256, 0, stream>>>(wproj, wprojT, 1024, 1024);
    qkv_gemm_kernel<<<dim3(64, 24), 256, 0, stream>>>(xb, wqkvT, bqkv, q2, k2, v2);
    attn_kernel<<<1024, 128, 0, stream>>>(q2, k2, v2, y);
    proj_gemm_kernel<<<dim3(64, 8), 256, 0, stream>>>(y, wprojT, bproj, out);
}

// Round 12
// 172.240 us; speedup vs baseline: 1.6324x; 1.0703x over previous
//
#include <hip/hip_runtime.h>

// B=4, L=2048, D=1024, H=16, HD=64.
// d_in fp32: x, Wqkv, bqkv, Wproj, bproj. d_out fp32.
// Pipeline: fp32->bf16 converts, m97-style bf16 MFMA GEMMs (global_load_lds),
// swapped-operand LDS-free causal flash attention with lane-major tiled
// Q2/K2/V2 (every fragment load = base+lane*16 coalesced). XCD bh-pinned.
// QKV epilogue: LDS-staged tiled-image -> 1KB coalesced 16B stores.
//
// Q2/K2 layout (bf16): addr(bh,l,hd) = ((bh*64 + (l>>5))*4 + (hd>>4))*512
//                                      + ((hd>>3)&1)*256 + (l&31)*8 + (hd&7)
// V2 layout (bf16):    addr(bh,l,hd) = ((bh*64 + (l>>5))*4 + (hd>>5)*2
//                                      + ((l>>4)&1))*512 + ((l>>2)&1)*256
//                                      + (hd&31)*8 + ((l&3)|(((l>>3)&1)<<2))

typedef __bf16 bf16x2 __attribute__((ext_vector_type(2)));
typedef __bf16 bf16x8 __attribute__((ext_vector_type(8)));
typedef float f32x4 __attribute__((ext_vector_type(4)));
typedef float f32x16 __attribute__((ext_vector_type(16)));
typedef unsigned u32x4 __attribute__((ext_vector_type(4)));

#define MFMA16(a, b, c) __builtin_amdgcn_mfma_f32_16x16x32_bf16(a, b, c, 0, 0, 0)
#define MFMA32(a, b, c) __builtin_amdgcn_mfma_f32_32x32x16_bf16(a, b, c, 0, 0, 0)

__device__ __forceinline__ void gload_lds16(const __bf16* g, __bf16* l) {
    __builtin_amdgcn_global_load_lds(
        (const __attribute__((address_space(1))) void*)g,
        (__attribute__((address_space(3))) void*)l, 16, 0, 0);
}

__device__ __forceinline__ unsigned pkbf(float a, float b) {
    bf16x2 t = {(__bf16)a, (__bf16)b};
    return __builtin_bit_cast(unsigned, t);
}

// ---------------------------------------------------------------------------
__global__ void convert_kernel(const float* __restrict__ in, __bf16* __restrict__ out)
{
    int i = (blockIdx.x * 256 + threadIdx.x) * 8;
    f32x4 lo = *(const f32x4*)&in[i];
    f32x4 hi = *(const f32x4*)&in[i + 4];
    bf16x8 o;
#pragma unroll
    for (int j = 0; j < 4; ++j) { o[j] = (__bf16)lo[j]; o[j + 4] = (__bf16)hi[j]; }
    *(bf16x8*)&out[i] = o;
}

// ---------------------------------------------------------------------------
__global__ void transpose_convert_kernel(const float* __restrict__ in,
                                         __bf16* __restrict__ out, int R, int C)
{
    __shared__ __bf16 t[32][33];
    const int c0 = blockIdx.x * 32, r0 = blockIdx.y * 32;
    const int tx = threadIdx.x & 31, ty = threadIdx.x >> 5;
#pragma unroll
    for (int j = 0; j < 4; ++j) {
        int r = ty + j * 8;
        t[tx][r] = (__bf16)in[(size_t)(r0 + r) * C + c0 + tx];
    }
    __syncthreads();
#pragma unroll
    for (int j = 0; j < 4; ++j) {
        int r = ty + j * 8;
        out[(size_t)(c0 + r) * R + r0 + tx] = t[r][tx];
    }
}

// ---------------------------------------------------------------------------
// m97-style GEMM core (unchanged).
// ---------------------------------------------------------------------------
#define GEMM_TILE_LOOP(Abase, Bbase)                                               \
    for (int k0 = 0; k0 < 1024; k0 += 32) {                                        \
        __syncthreads();                                                           \
        _Pragma("unroll")                                                          \
        for (int i = 0; i < 2; ++i) {                                              \
            int wl = w * 2 + i;                                                    \
            int r = wl * 16 + (lane >> 2);                                         \
            int c = ((lane & 3) ^ ((r >> 1) & 3)) * 8;                             \
            gload_lds16(&Abase[(size_t)(m0 + r) * 1024 + k0 + c], &As[wl * 512]);  \
            gload_lds16(&Bbase[(size_t)(n0 + r) * 1024 + k0 + c], &Bs[wl * 512]);  \
        }                                                                          \
        __syncthreads();                                                           \
        bf16x8 af[4], bfr[4];                                                      \
        _Pragma("unroll")                                                          \
        for (int mf = 0; mf < 4; ++mf) {                                           \
            int rr = wr * 64 + mf * 16 + row;                                      \
            af[mf] = *(const bf16x8*)&As[rr * 32 + ((g ^ ((rr >> 1) & 3)) * 8)];   \
        }                                                                          \
        _Pragma("unroll")                                                          \
        for (int nf = 0; nf < 4; ++nf) {                                           \
            int rr = wc * 64 + nf * 16 + row;                                      \
            bfr[nf] = *(const bf16x8*)&Bs[rr * 32 + ((g ^ ((rr >> 1) & 3)) * 8)];  \
        }                                                                          \
        _Pragma("unroll")                                                          \
        for (int mf = 0; mf < 4; ++mf)                                             \
            _Pragma("unroll")                                                      \
            for (int nf = 0; nf < 4; ++nf)                                         \
                acc[mf][nf] = MFMA16(af[mf], bfr[nf], acc[mf][nf]);                \
    }

// QKV GEMM. LDS-staged epilogue -> coalesced 1KB chunk stores into Q2/K2/V2.
__global__ __launch_bounds__(256, 2)
void qkv_gemm_kernel(const __bf16* __restrict__ A, const __bf16* __restrict__ Bt,
                     const float* __restrict__ bias,
                     __bf16* __restrict__ q2, __bf16* __restrict__ k2,
                     __bf16* __restrict__ v2)
{
    __shared__ __bf16 stage[16384];           // 32 KB; K-loop uses first 16 KB
    __bf16* const As = stage;                 // 128*32
    __bf16* const Bs = stage + 4096;          // 128*32
    const int tid = threadIdx.x;
    const int lane = tid & 63;
    const int w = tid >> 6;
    const int wr = w >> 1, wc = w & 1;
    const int row = lane & 15, g = lane >> 4;
    const int m0 = blockIdx.x * 128;
    const int n0 = blockIdx.y * 128;

    const f32x4 fzero = {0.f, 0.f, 0.f, 0.f};
    f32x4 acc[4][4];
#pragma unroll
    for (int a = 0; a < 4; ++a)
#pragma unroll
        for (int b = 0; b < 4; ++b) acc[a][b] = fzero;

    GEMM_TILE_LOOP(A, Bt)

    // ---- epilogue: build tiled-layout image in LDS, then coalesced stores
    __syncthreads();   // all waves done reading As/Bs
    const int part = n0 >> 10;                // 0=q 1=k 2=v (uniform per block)
    const float QSCL = 0.18033688f;           // 0.125 * log2(e)
#pragma unroll
    for (int mf = 0; mf < 4; ++mf)
#pragma unroll
        for (int nf = 0; nf < 4; ++nf) {
            int nl = nf * 16 + row;
            float bv = bias[n0 + wc * 64 + nl];
#pragma unroll
            for (int i = 0; i < 4; ++i) {
                int ml = mf * 16 + g * 4 + i;
                float fv = acc[mf][nf][i] + bv;
                if (part == 0) fv *= QSCL;
                int c, off;
                if (part == 2) {
                    c = (ml >> 5) * 4 + (nl >> 5) * 2 + ((ml >> 4) & 1);
                    off = ((ml >> 2) & 1) * 256 + (nl & 31) * 8 +
                          ((ml & 3) | (((ml >> 3) & 1) << 2));
                } else {
                    c = (ml >> 5) * 4 + (nl >> 4);
                    off = ((nl >> 3) & 1) * 256 + (ml & 31) * 8 + (nl & 7);
                }
                stage[w * 4096 + c * 512 + off] = (__bf16)fv;
            }
        }
    // store phase: each wave streams its own 8 chunks (1KB each, coalesced)
    {
        const int b = m0 >> 11;
        const int lbase5 = (m0 & 2047) >> 5;
        const int hh = ((n0 & 1023) >> 6) + wc;
        const size_t bh64 = (size_t)(b * 16 + hh) * 64;
        __bf16* dst = part == 0 ? q2 : (part == 1 ? k2 : v2);
#pragma unroll
        for (int c = 0; c < 8; ++c) {
            bf16x8 val = *(const bf16x8*)&stage[w * 4096 + c * 512 + lane * 8];
            size_t gbase = ((bh64 + lbase5 + wr * 2 + (c >> 2)) * 4 + (c & 3)) * 512;
            *(bf16x8*)&dst[gbase + lane * 8] = val;
        }
    }
}

__global__ __launch_bounds__(256, 2)
void proj_gemm_kernel(const __bf16* __restrict__ A, const __bf16* __restrict__ Bt,
                      const float* __restrict__ bias, float* __restrict__ out)
{
    __shared__ __bf16 As[128 * 32];
    __shared__ __bf16 Bs[128 * 32];
    const int tid = threadIdx.x;
    const int lane = tid & 63;
    const int w = tid >> 6;
    const int wr = w >> 1, wc = w & 1;
    const int row = lane & 15, g = lane >> 4;
    const int m0 = blockIdx.x * 128;
    const int n0 = blockIdx.y * 128;

    const f32x4 fzero = {0.f, 0.f, 0.f, 0.f};
    f32x4 acc[4][4];
#pragma unroll
    for (int a = 0; a < 4; ++a)
#pragma unroll
        for (int b = 0; b < 4; ++b) acc[a][b] = fzero;

    GEMM_TILE_LOOP(A, Bt)

#pragma unroll
    for (int mf = 0; mf < 4; ++mf)
#pragma unroll
        for (int nf = 0; nf < 4; ++nf) {
            int n = n0 + wc * 64 + nf * 16 + row;
            float bv = bias[n];
#pragma unroll
            for (int i = 0; i < 4; ++i) {
                int mm = m0 + wr * 64 + mf * 16 + g * 4 + i;
                out[(size_t)mm * 1024 + n] = acc[mf][nf][i] + bv;
            }
        }
}

// ---------------------------------------------------------------------------
// Pair-balanced swapped-operand causal flash attention (R7 structure),
// lane-major tiled Q2/K2/V2 -> every load is base+lane*16 (coalesced).
// 1D grid 1024 blocks, 128 thr = 2 waves. XCD pin: bh = (i&7)*8+((i>>3)&7).
// Wave wv owns q-tiles t = 2*(i>>6)+wv and 63-t (65 k-tile units each).
// ---------------------------------------------------------------------------
__global__ __launch_bounds__(128, 2)
void attn_kernel(const __bf16* __restrict__ Q2, const __bf16* __restrict__ K2,
                 const __bf16* __restrict__ V2, __bf16* __restrict__ Yw)
{
    const int tid = threadIdx.x;
    const int lane = tid & 63;
    const int wv = tid >> 6;
    const int col = lane & 31;
    const int hi = lane >> 5;
    const int i0 = blockIdx.x;
    const int bh = (i0 & 7) * 8 + ((i0 >> 3) & 7);
    const int t = (i0 >> 6) * 2 + wv;          // 0..31
    const int qA = t * 32;
    const int qB = (63 - t) * 32;
    const size_t tb = (size_t)bh * 64;         // tile base

    bf16x8 qfA[4], qfB[4];
#pragma unroll
    for (int dc = 0; dc < 4; ++dc) {
        qfA[dc] = *(const bf16x8*)&Q2[((tb + t) * 4 + dc) * 512 + lane * 8];
        qfB[dc] = *(const bf16x8*)&Q2[((tb + 63 - t) * 4 + dc) * 512 + lane * 8];
    }

    f32x16 OtA[2], OtB[2];
#pragma unroll
    for (int dt = 0; dt < 2; ++dt)
#pragma unroll
        for (int i = 0; i < 16; ++i) { OtA[dt][i] = 0.f; OtB[dt][i] = 0.f; }
    float mA = -__builtin_inff(), lA = 0.f;
    float mB = -__builtin_inff(), lB = 0.f;

    auto smxpack = [&](f32x16& st, float& m, float& lsum, f32x16* Ot,
                       bool diag, bf16x8& pa0, bf16x8& pa1) {
        if (diag) {
#pragma unroll
            for (int r = 0; r < 16; ++r) {
                int crow = (r & 3) + 8 * (r >> 2) + 4 * hi;
                if (crow > col) st[r] = -1e30f;
            }
        }
        float a0 = fmaxf(fmaxf(st[0], st[1]), st[2]);
        float a1 = fmaxf(fmaxf(st[3], st[4]), st[5]);
        float a2 = fmaxf(fmaxf(st[6], st[7]), st[8]);
        float a3 = fmaxf(fmaxf(st[9], st[10]), st[11]);
        float a4 = fmaxf(st[12], st[13]);
        float a5 = fmaxf(st[14], st[15]);
        float pmax = fmaxf(fmaxf(fmaxf(a0, a1), fmaxf(a2, a3)), fmaxf(a4, a5));
        pmax = fmaxf(pmax, __shfl_xor(pmax, 32, 64));
        if (!__all(pmax - m <= 8.0f)) {
            float mnew = fmaxf(m, pmax);
            float alpha = exp2f(m - mnew);
#pragma unroll
            for (int dt = 0; dt < 2; ++dt)
#pragma unroll
                for (int i = 0; i < 16; ++i) Ot[dt][i] *= alpha;
            lsum *= alpha;
            m = mnew;
        }
#pragma unroll
        for (int r = 0; r < 16; ++r) st[r] = exp2f(st[r] - m);
        float s0 = (st[0] + st[1]) + (st[2] + st[3]);
        float s1 = (st[4] + st[5]) + (st[6] + st[7]);
        float s2 = (st[8] + st[9]) + (st[10] + st[11]);
        float s3 = (st[12] + st[13]) + (st[14] + st[15]);
        float rs = (s0 + s1) + (s2 + s3);
        rs += __shfl_xor(rs, 32, 64);
        lsum += rs;
        u32x4 w0 = {pkbf(st[0], st[1]), pkbf(st[2], st[3]),
                    pkbf(st[4], st[5]), pkbf(st[6], st[7])};
        u32x4 w1 = {pkbf(st[8], st[9]), pkbf(st[10], st[11]),
                    pkbf(st[12], st[13]), pkbf(st[14], st[15])};
        pa0 = __builtin_bit_cast(bf16x8, w0);
        pa1 = __builtin_bit_cast(bf16x8, w1);
    };

    bf16x8 kf[4];
#pragma unroll
    for (int dc = 0; dc < 4; ++dc)
        kf[dc] = *(const bf16x8*)&K2[(tb * 4 + dc) * 512 + lane * 8];

    for (int kb = 0; kb <= qB; kb += 32) {
        const int kt = kb >> 5;
        const bool dual = (kb <= qA);
        bf16x8 vf[4];
#pragma unroll
        for (int dt = 0; dt < 2; ++dt)
#pragma unroll
            for (int half = 0; half < 2; ++half)
                vf[dt * 2 + half] = *(const bf16x8*)
                    &V2[((tb + kt) * 4 + dt * 2 + half) * 512 + lane * 8];

        f32x16 stA, stB;
#pragma unroll
        for (int i = 0; i < 16; ++i) { stA[i] = 0.f; stB[i] = 0.f; }
        __builtin_amdgcn_s_setprio(1);
        if (dual) {
#pragma unroll
            for (int dc = 0; dc < 4; ++dc) {
                stB = MFMA32(kf[dc], qfB[dc], stB);
                stA = MFMA32(kf[dc], qfA[dc], stA);
            }
        } else {
#pragma unroll
            for (int dc = 0; dc < 4; ++dc)
                stB = MFMA32(kf[dc], qfB[dc], stB);
        }
        __builtin_amdgcn_s_setprio(0);

        const int ktn = (kb + 32 <= qB) ? kt + 1 : kt;
        bf16x8 kfn[4];
#pragma unroll
        for (int dc = 0; dc < 4; ++dc)
            kfn[dc] = *(const bf16x8*)&K2[((tb + ktn) * 4 + dc) * 512 + lane * 8];

        bf16x8 paA0, paA1, paB0, paB1;
        smxpack(stB, mB, lB, OtB, kb == qB, paB0, paB1);
        if (dual) smxpack(stA, mA, lA, OtA, kb == qA, paA0, paA1);

        __builtin_amdgcn_s_setprio(1);
#pragma unroll
        for (int dt = 0; dt < 2; ++dt) {
            OtB[dt] = MFMA32(vf[dt * 2 + 0], paB0, OtB[dt]);
            OtB[dt] = MFMA32(vf[dt * 2 + 1], paB1, OtB[dt]);
            if (dual) {
                OtA[dt] = MFMA32(vf[dt * 2 + 0], paA0, OtA[dt]);
                OtA[dt] = MFMA32(vf[dt * 2 + 1], paA1, OtA[dt]);
            }
        }
        __builtin_amdgcn_s_setprio(0);

#pragma unroll
        for (int dc = 0; dc < 4; ++dc) kf[dc] = kfn[dc];
    }

    const int b = bh >> 4, h = bh & 15;
    const float invA = 1.f / lA, invB = 1.f / lB;
    __bf16* yrowA = Yw + ((size_t)(b * 2048 + qA + col)) * 1024 + h * 64;
    __bf16* yrowB = Yw + ((size_t)(b * 2048 + qB + col)) * 1024 + h * 64;
#pragma unroll
    for (int dt = 0; dt < 2; ++dt)
#pragma unroll
        for (int rg = 0; rg < 4; ++rg) {
            int d0 = dt * 32 + rg * 8 + hi * 4;
            unsigned lo = pkbf(OtA[dt][rg * 4 + 0] * invA, OtA[dt][rg * 4 + 1] * invA);
            unsigned h2 = pkbf(OtA[dt][rg * 4 + 2] * invA, OtA[dt][rg * 4 + 3] * invA);
            *(unsigned long long*)&yrowA[d0] =
                (unsigned long long)lo | ((unsigned long long)h2 << 32);
            lo = pkbf(OtB[dt][rg * 4 + 0] * invB, OtB[dt][rg * 4 + 1] * invB);
            h2 = pkbf(OtB[dt][rg * 4 + 2] * invB, OtB[dt][rg * 4 + 3] * invB);
            *(unsigned long long*)&yrowB[d0] =
                (unsigned long long)lo | ((unsigned long long)h2 << 32);
        }
}

// ---------------------------------------------------------------------------
extern "C" void kernel_launch(void* const* d_in, const int* in_sizes, int n_in,
                              void* d_out, int out_size, void* d_ws, size_t ws_size,
                              hipStream_t stream)
{
    const float* x     = (const float*)d_in[0];
    const float* wqkv  = (const float*)d_in[1];
    const float* bqkv  = (const float*)d_in[2];
    const float* wproj = (const float*)d_in[3];
    const float* bproj = (const float*)d_in[4];
    float* out = (float*)d_out;

    const size_t E = (size_t)4 * 16 * 2048 * 64;
    __bf16* q2     = (__bf16*)d_ws;               // E (pre-scaled, tiled)
    __bf16* k2     = q2 + E;                      // E (tiled)
    __bf16* v2     = k2 + E;                      // E (tiled, PV k-placement)
    __bf16* xb     = v2 + E;                      // E
    __bf16* y      = xb;                          // alias
    __bf16* wqkvT  = xb + E;
    __bf16* wprojT = wqkvT + (size_t)3072 * 1024;

    convert_kernel<<<4096, 256, 0, stream>>>(x, xb);
    transpose_convert_kernel<<<dim3(96, 32), 256, 0, stream>>>(wqkv, wqkvT, 1024, 3072);
    transpose_convert_kernel<<<dim3(32, 32), 256, 0, stream>>>(wproj, wprojT, 1024, 1024);
    qkv_gemm_kernel<<<dim3(64, 24), 256, 0, stream>>>(xb, wqkvT, bqkv, q2, k2, v2);
    attn_kernel<<<1024, 128, 0, stream>>>(q2, k2, v2, y);
    proj_gemm_kernel<<<dim3(64, 8), 256, 0, stream>>>(y, wprojT, bproj, out);
}